// Round 13
// baseline (344.459 us; speedup 1.0000x reference)
//
#include <hip/hip_runtime.h>

// ---------------- problem constants ----------------
#define NM      2          // NMODES
#define STEPS_C 5
#define DTAPS_C 1001
#define NTAPS_C 101
#define HID_C   100
#define B_C     4
#define SEQ_C   500000
#define SSTR    SEQ_C      // per-(b,mode) stride in planar work buffers
#define NKP     104        // nonlinear taps padded to multiple of 8 (zeros)
#define FS_NOM_D 160000000000.0
#define PI_D 3.14159265358979323846

// LDS bank swizzle for nl_rotate: insert 4 pad floats every 32
#define SWZ(L) ((L) + ((((unsigned)(L)) >> 5) << 2))

#define LD4V(A0,A1,A2,A3, SRC) { float4 q_ = *(const float4*)&(SRC); \
    A0=q_.x; A1=q_.y; A2=q_.z; A3=q_.w; }

// complex multiply helper (outputs must not alias inputs)
__device__ __forceinline__ void cmulf(float& o_r, float& o_i,
                                      float a_r, float a_i, float b_r, float b_i)
{ o_r = a_r * b_r - a_i * b_i; o_i = a_r * b_i + a_i * b_r; }

// ---------------- dispersion kernel build (parallel DFT) ----------------
// grid (32, B), 256 thr. Block stages the 1001 freq-domain samples (fp64) in
// LDS; 32 outputs/block, 8-way k-split per output, shfl_xor reduce.
__global__ void build_disp(const float* __restrict__ task,
                           float* __restrict__ HR, float* __restrict__ HI)
{
    __shared__ double skr[DTAPS_C], ski[DTAPS_C];
    const int b = blockIdx.y;
    const double Fs = (double)task[b * 4 + 2];
    const double c_kms = 299792458.0 / 1000.0;
    const double Fc    = 299792458.0 / 1.55e-6;
    const double lamb  = c_kms / Fc;
    const double beta2 = -(16.5 * lamb * lamb) / (2.0 * PI_D * c_kms) / 1000.0;
    const double dz    = -400000.0;   // -(L_FIBER/STEP)

    for (int k = threadIdx.x; k < DTAPS_C; k += blockDim.x) {
        double fk = ((k <= DTAPS_C / 2) ? (double)k : (double)(k - DTAPS_C)) / (double)DTAPS_C;
        double om = 2.0 * PI_D * Fs * fk;
        double ph = 0.5 * beta2 * om * om * dz;
        ph = fmod(ph, 2.0 * PI_D);
        double s, c; sincos(ph, &s, &c);
        skr[k] = c;  ski[k] = -s;     // exp(-i*phase)
    }
    __syncthreads();

    const int ln = threadIdx.x >> 3;           // 0..31 output slot
    const int kp = threadIdx.x & 7;            // 0..7  k-part
    const int n  = blockIdx.x * 32 + ln;       // 0..1023
    double dr = 0.0, di = 0.0;
    {
        const int nn = (n < DTAPS_C) ? n : 0;
        // twiddle e^{+2pi i k n/1001}: start at k=kp, step 8
        const int r0 = (nn * kp) % DTAPS_C;
        const int rs = (nn * 8) % DTAPS_C;
        double a0 = 2.0 * PI_D * (double)r0 / (double)DTAPS_C;
        double as = 2.0 * PI_D * (double)rs / (double)DTAPS_C;
        double s0, c0, ss, cs;
        sincos(a0, &s0, &c0);
        sincos(as, &ss, &cs);
        for (int k = kp; k < DTAPS_C; k += 8) {
            dr += skr[k] * c0 - ski[k] * s0;
            di += skr[k] * s0 + ski[k] * c0;
            const double nc = c0 * cs - s0 * ss;
            s0 = c0 * ss + s0 * cs;
            c0 = nc;
        }
    }
    // reduce over kp (lanes differing in low 3 bits share one n)
    #pragma unroll
    for (int m = 1; m <= 4; m <<= 1) {
        dr += __shfl_xor(dr, m, 64);
        di += __shfl_xor(di, m, 64);
    }
    if (kp == 0 && n < DTAPS_C) {
        int m = n + DTAPS_C / 2; if (m >= DTAPS_C) m -= DTAPS_C;  // fftshift
        HR[b * DTAPS_C + m] = (float)(dr / (double)DTAPS_C);
        HI[b * DTAPS_C + m] = (float)(di / (double)DTAPS_C);
    }
}

// ---------------- filter spectrum for overlap-save FFT conv ----------------
// G[f] = (1/4096) * sum_k h[k] * e^{+2pi i f k / 4096}, stored at the
// digit-reversed (base-16, 3 digits) position so the FFT needs no reorder.
// grid (128, B), 256 thr: 32 outputs/block, 8-way k-split, shfl_xor reduce.
__global__ void build_G(const float* __restrict__ HR, const float* __restrict__ HI,
                        float* __restrict__ Gb)
{
    __shared__ float shr[DTAPS_C], shi[DTAPS_C];
    const int b = blockIdx.y;
    for (int k = threadIdx.x; k < DTAPS_C; k += blockDim.x) {
        shr[k] = HR[b * DTAPS_C + k];
        shi[k] = HI[b * DTAPS_C + k];
    }
    __syncthreads();

    const int ln = threadIdx.x >> 3;
    const int kp = threadIdx.x & 7;
    const int f  = blockIdx.x * 32 + ln;       // 0..4095
    double ar = 0.0, ai = 0.0;
    {
        // twiddle e^{+2pi i f k/4096}: start k=kp, step 8
        const int r0 = (f * kp) & 4095;
        const int rs = (f * 8) & 4095;
        double a0 = (2.0 * PI_D / 4096.0) * (double)r0;
        double as = (2.0 * PI_D / 4096.0) * (double)rs;
        double s0, c0, ss, cs;
        sincos(a0, &s0, &c0);
        sincos(as, &ss, &cs);
        for (int k = kp; k < DTAPS_C; k += 8) {
            const double hre = (double)shr[k], him = (double)shi[k];
            ar += hre * c0 - him * s0;
            ai += hre * s0 + him * c0;
            const double nc = c0 * cs - s0 * ss;
            s0 = c0 * ss + s0 * cs;
            c0 = nc;
        }
    }
    #pragma unroll
    for (int m = 1; m <= 4; m <<= 1) {
        ar += __shfl_xor(ar, m, 64);
        ai += __shfl_xor(ai, m, 64);
    }
    if (kp == 0) {
        const int p = ((f & 15) << 8) + (((f >> 4) & 15) << 4) + (f >> 8);
        Gb[(size_t)(b * 4096 + p) * 2 + 0] = (float)(ar * (1.0 / 4096.0));
        Gb[(size_t)(b * 4096 + p) * 2 + 1] = (float)(ai * (1.0 / 4096.0));
    }
}

// ---------------- nonlinear kernel build (tiny MLP) ----------------
__global__ void build_nk(const float* __restrict__ task,
                         const float* __restrict__ W1, const float* __restrict__ b1,
                         const float* __restrict__ W2, const float* __restrict__ b2,
                         float* __restrict__ NKg, float* __restrict__ COEF)
{
    const int tid = threadIdx.x;
    for (int i = tid; i < B_C * 4 * NKP; i += blockDim.x) NKg[i] = 0.f;
    if (tid < B_C) {
        float pdbm = task[tid * 4 + 0];
        float P = 0.001f * powf(10.f, pdbm * 0.1f) / (float)NM;
        COEF[tid] = (float)(0.0016567 * 400000.0) * P;  // GAMMA*DZ*P
    }
    __syncthreads();
    if (tid < B_C * NTAPS_C) {
        const int b = tid / NTAPS_C, tap = tid % NTAPS_C;
        float Fsn = task[b * 4 + 2] * (float)(1.0 / FS_NOM_D);
        float Ts = 1.f / Fsn, Ts2 = Ts * Ts;
        float pos = fabsf((float)(tap - NTAPS_C / 2)) * (1.f / 200.f);
        float inp = pos * Ts2;
        float o0 = b2[0], o1 = b2[1], o2 = b2[2], o3 = b2[3];
        for (int j = 0; j < HID_C; ++j) {
            float h = fmaxf(fmaf(inp, W1[j], b1[j]), 0.f);
            o0 = fmaf(h, W2[j * 4 + 0], o0);
            o1 = fmaf(h, W2[j * 4 + 1], o1);
            o2 = fmaf(h, W2[j * 4 + 2], o2);
            o3 = fmaf(h, W2[j * 4 + 3], o3);
        }
        float sc = Ts2 * expf(-pos * Ts2);
        NKg[(b * 4 + 0) * NKP + tap] = o0 * sc;
        NKg[(b * 4 + 1) * NKP + tap] = o1 * sc;
        NKg[(b * 4 + 2) * NKP + tap] = o2 * sc;
        NKg[(b * 4 + 3) * NKP + tap] = o3 * sc;
    }
}

// ---------------- input transpose (B,SEQ,2) -> planar (B,2,SEQ) -------------
__global__ void transpose_in(const float* __restrict__ xr_in, const float* __restrict__ xi_in,
                             float* __restrict__ XR, float* __restrict__ XI)
{
    int idx = blockIdx.x * blockDim.x + threadIdx.x;   // over B*SEQ
    if (idx >= B_C * SEQ_C) return;
    int b = idx / SEQ_C, t = idx - b * SEQ_C;
    float2 vr = ((const float2*)xr_in)[idx];
    float2 vi = ((const float2*)xi_in)[idx];
    XR[(size_t)(b * 2 + 0) * SSTR + t] = vr.x;
    XR[(size_t)(b * 2 + 1) * SSTR + t] = vr.y;
    XI[(size_t)(b * 2 + 0) * SSTR + t] = vi.x;
    XI[(size_t)(b * 2 + 1) * SSTR + t] = vi.y;
}

// ---------------- radix-16 building blocks (all-register, static idx) -------
template<int SGN>
__device__ __forceinline__ void dft4(float& ar, float& ai, float& br, float& bi,
                                     float& cr, float& ci, float& dr, float& di)
{
    float t0r = ar + cr, t0i = ai + ci;
    float t1r = ar - cr, t1i = ai - ci;
    float t2r = br + dr, t2i = bi + di;
    float t3r = br - dr, t3i = bi - di;
    ar = t0r + t2r; ai = t0i + t2i;          // y0
    cr = t0r - t2r; ci = t0i - t2i;          // y2
    if (SGN < 0) {                           // fwd: y1 = t1 - i t3, y3 = t1 + i t3
        br = t1r + t3i; bi = t1i - t3r;
        dr = t1r - t3i; di = t1i + t3r;
    } else {                                 // inv: conj
        br = t1r - t3i; bi = t1i + t3r;
        dr = t1r + t3i; di = t1i - t3r;
    }
}

template<int SGN>
__device__ __forceinline__ void tw16(float& r, float& i, float c, float s)
{
    // multiply by (c + SGN * i * s)
    float nr, ni;
    if (SGN < 0) { nr = r * c + i * s; ni = i * c - r * s; }
    else         { nr = r * c - i * s; ni = i * c + r * s; }
    r = nr; i = ni;
}

// In-place DFT16. Input x[m] at slot m; output X[k1+4k2] lands at slot 4*k1+k2
// i.e. X[k] at slot SIG(k) = 4*(k&3)+(k>>2) (an involution).
template<int SGN>
__device__ __forceinline__ void dft16(float (&xr)[16], float (&xi)[16])
{
    #pragma unroll
    for (int n1 = 0; n1 < 4; ++n1)
        dft4<SGN>(xr[n1], xi[n1], xr[n1+4], xi[n1+4],
                  xr[n1+8], xi[n1+8], xr[n1+12], xi[n1+12]);
    const float C1 = 0.923879532511286756f, S1 = 0.382683432365089772f;
    const float C2 = 0.707106781186547524f;
    tw16<SGN>(xr[5],  xi[5],  C1,  S1);      // w16^1
    tw16<SGN>(xr[9],  xi[9],  C2,  C2);      // w16^2
    tw16<SGN>(xr[13], xi[13], S1,  C1);      // w16^3
    tw16<SGN>(xr[6],  xi[6],  C2,  C2);      // w16^2
    tw16<SGN>(xr[10], xi[10], 0.f, 1.f);     // w16^4
    tw16<SGN>(xr[14], xi[14], -C2, C2);      // w16^6
    tw16<SGN>(xr[7],  xi[7],  S1,  C1);      // w16^3
    tw16<SGN>(xr[11], xi[11], -C2, C2);      // w16^6
    tw16<SGN>(xr[15], xi[15], -C1, -S1);     // w16^9
    #pragma unroll
    for (int k4 = 0; k4 < 4; ++k4)
        dft4<SGN>(xr[4*k4+0], xi[4*k4+0], xr[4*k4+1], xi[4*k4+1],
                  xr[4*k4+2], xi[4*k4+2], xr[4*k4+3], xi[4*k4+3]);
}

// Log-depth 16-twiddle ladder: given w = (c,s), derive w^2, w^3, w^4 once;
// tw_k = w^{4g} * w^{k&3}. Serial dependency depth ~5 complex mults instead
// of the 15-step recurrence (which throttled ILP in the store loops).
#define TWLADDER_INIT(c_, s_)                                              \
    float w1r_ = (c_), w1i_ = (s_), w2r_, w2i_, w3r_, w3i_, w4r_, w4i_;    \
    cmulf(w2r_, w2i_, w1r_, w1i_, w1r_, w1i_);                             \
    cmulf(w3r_, w3i_, w2r_, w2i_, w1r_, w1i_);                             \
    cmulf(w4r_, w4i_, w2r_, w2i_, w2r_, w2i_);                             \
    float bgr_ = 1.f, bgi_ = 0.f;

#define TWLADDER_GET(k_, twr_, twi_)                                       \
    {                                                                      \
        const int j_ = (k_) & 3;                                           \
        if      (j_ == 0) { twr_ = bgr_; twi_ = bgi_; }                    \
        else if (j_ == 1) cmulf(twr_, twi_, bgr_, bgi_, w1r_, w1i_);       \
        else if (j_ == 2) cmulf(twr_, twi_, bgr_, bgi_, w2r_, w2i_);       \
        else              cmulf(twr_, twi_, bgr_, bgi_, w3r_, w3i_);       \
    }

#define TWLADDER_STEP(k_)                                                  \
    if (((k_) & 3) == 3 && (k_) < 15) {                                    \
        float nr_, ni_;                                                    \
        cmulf(nr_, ni_, bgr_, bgi_, w4r_, w4i_);                           \
        bgr_ = nr_; bgi_ = ni_;                                            \
    }

// ---------------- dispersion via overlap-save FFT ----------------
// N=4096=16^3 complex FFT, 256 threads, one 16-pt DFT per thread per stage.
// (round-11 version verbatim — the ilv branch of round 12 regressed codegen)
#define FFTN  4096
#define FSTEP 3096                 // valid outputs per segment (4096-1001+1)
#define PH(i) ((i) + ((((unsigned)(i)) >> 5) << 1))
#define LDSN  4352                 // PH(4095)=4349, rounded up

__global__ __launch_bounds__(256, 2) void disp_fft(
    const float* __restrict__ XR, const float* __restrict__ XI,
    const float* __restrict__ Gb,
    float* __restrict__ AR, float* __restrict__ AI, int La)
{
    __shared__ __align__(16) float sre[LDSN];
    __shared__ __align__(16) float sim[LDSN];
    const int t = threadIdx.x;
    const int seq = blockIdx.y;           // b*2 + mode
    const int b = seq >> 1;
    const int tile0 = blockIdx.x * FSTEP;
    const int Lin = La + (DTAPS_C - 1);   // current input length
    const int rem_in = Lin - tile0;       // >= 1001
    const float* xr = XR + (size_t)seq * SSTR + tile0;
    const float* xi = XI + (size_t)seq * SSTR + tile0;

    // ---- load segment (zero-padded tail) ----
    #pragma unroll
    for (int q = 0; q < 4; ++q) {
        const int i0 = q * 1024 + t * 4;
        float4 vr4 = make_float4(0.f, 0.f, 0.f, 0.f);
        float4 vi4 = make_float4(0.f, 0.f, 0.f, 0.f);
        if (i0 + 3 < rem_in) {
            vr4 = *(const float4*)(xr + i0);
            vi4 = *(const float4*)(xi + i0);
        } else {
            if (i0 + 0 < rem_in) { vr4.x = xr[i0+0]; vi4.x = xi[i0+0]; }
            if (i0 + 1 < rem_in) { vr4.y = xr[i0+1]; vi4.y = xi[i0+1]; }
            if (i0 + 2 < rem_in) { vr4.z = xr[i0+2]; vi4.z = xi[i0+2]; }
        }
        const int p = PH(i0);             // i0%32 <= 28 -> 4 contiguous
        sre[p+0] = vr4.x; sre[p+1] = vr4.y; sre[p+2] = vr4.z; sre[p+3] = vr4.w;
        sim[p+0] = vi4.x; sim[p+1] = vi4.y; sim[p+2] = vi4.z; sim[p+3] = vi4.w;
    }
    __syncthreads();

    float vr[16], vi[16];

    // ---- FWD stage 1: L=4096, j=t, addr = t + 256*m -> PH = PH(t) + 272*m
    {
        const int base = PH(t);
        #pragma unroll
        for (int m = 0; m < 16; ++m) { vr[m] = sre[base + 272*m]; vi[m] = sim[base + 272*m]; }
        dft16<-1>(vr, vi);
        float s, c; sincosf((float)(-2.0 * PI_D / 4096.0) * (float)t, &s, &c);
        TWLADDER_INIT(c, s)
        #pragma unroll
        for (int k = 0; k < 16; ++k) {
            const int sl = 4*(k&3) + (k>>2);
            float twr, twi;
            TWLADDER_GET(k, twr, twi)
            sre[base + 272*k] = vr[sl]*twr - vi[sl]*twi;
            sim[base + 272*k] = vr[sl]*twi + vi[sl]*twr;
            TWLADDER_STEP(k)
        }
    }
    __syncthreads();

    // ---- FWD stage 2: L=256, blk=t>>4, j=t&15, addr = 256blk + j + 16m
    {
        const int j = t & 15, blk = t >> 4;
        const int base = 272*blk + j;
        #pragma unroll
        for (int m = 0; m < 16; ++m) {
            const int o = base + 16*m + 2*(m>>1);
            vr[m] = sre[o]; vi[m] = sim[o];
        }
        dft16<-1>(vr, vi);
        float s, c; sincosf((float)(-2.0 * PI_D / 256.0) * (float)j, &s, &c);
        TWLADDER_INIT(c, s)
        #pragma unroll
        for (int k = 0; k < 16; ++k) {
            const int sl = 4*(k&3) + (k>>2);
            const int o = base + 16*k + 2*(k>>1);
            float twr, twi;
            TWLADDER_GET(k, twr, twi)
            sre[o] = vr[sl]*twr - vi[sl]*twi;
            sim[o] = vr[sl]*twi + vi[sl]*twr;
            TWLADDER_STEP(k)
        }
    }
    __syncthreads();

    // ---- fused: FWD stage 3 (contig 16, no twiddle) + G multiply + INV stage 3
    {
        const int base = 16*t + 2*(t>>1);    // PH(16t + m) = base + m
        #pragma unroll
        for (int m = 0; m < 16; ++m) { vr[m] = sre[base + m]; vi[m] = sim[base + m]; }
        dft16<-1>(vr, vi);
        const float2* gp = ((const float2*)Gb) + ((size_t)b << 12) + (t << 4);
        float wr2[16], wi2[16];
        #pragma unroll
        for (int k = 0; k < 16; ++k) {
            const int sl = 4*(k&3) + (k>>2);
            const float2 g = gp[k];          // G at digit-reversed pos 16t+k
            wr2[k] = vr[sl]*g.x - vi[sl]*g.y;
            wi2[k] = vr[sl]*g.y + vi[sl]*g.x;
        }
        dft16<1>(wr2, wi2);
        #pragma unroll
        for (int m = 0; m < 16; ++m) {
            const int sl = 4*(m&3) + (m>>2);
            sre[base + m] = wr2[sl]; sim[base + m] = wi2[sl];
        }
    }
    __syncthreads();

    // ---- INV stage 2': conj twiddle on input, iDFT16, write to m-slots
    {
        const int j = t & 15, blk = t >> 4;
        const int base = 272*blk + j;
        float s, c; sincosf((float)(2.0 * PI_D / 256.0) * (float)j, &s, &c);
        TWLADDER_INIT(c, s)
        #pragma unroll
        for (int k = 0; k < 16; ++k) {
            const int o = base + 16*k + 2*(k>>1);
            const float a = sre[o], d = sim[o];
            float twr, twi;
            TWLADDER_GET(k, twr, twi)
            vr[k] = a*twr - d*twi; vi[k] = a*twi + d*twr;
            TWLADDER_STEP(k)
        }
        dft16<1>(vr, vi);
        #pragma unroll
        for (int m = 0; m < 16; ++m) {
            const int sl = 4*(m&3) + (m>>2);
            const int o = base + 16*m + 2*(m>>1);
            sre[o] = vr[sl]; sim[o] = vi[sl];
        }
    }
    __syncthreads();

    // ---- INV stage 1'
    {
        const int base = PH(t);
        float s, c; sincosf((float)(2.0 * PI_D / 4096.0) * (float)t, &s, &c);
        TWLADDER_INIT(c, s)
        #pragma unroll
        for (int k = 0; k < 16; ++k) {
            const float a = sre[base + 272*k], d = sim[base + 272*k];
            float twr, twi;
            TWLADDER_GET(k, twr, twi)
            vr[k] = a*twr - d*twi; vi[k] = a*twi + d*twr;
            TWLADDER_STEP(k)
        }
        dft16<1>(vr, vi);
        #pragma unroll
        for (int m = 0; m < 16; ++m) {
            const int sl = 4*(m&3) + (m>>2);
            sre[base + 272*m] = vr[sl]; sim[base + 272*m] = vi[sl];
        }
    }
    __syncthreads();

    // ---- store valid outputs [0, nout) ----
    const int nout = min(FSTEP, La - tile0);
    float* arp = AR + (size_t)seq * SSTR + tile0;
    float* aip = AI + (size_t)seq * SSTR + tile0;
    #pragma unroll
    for (int q = 0; q < 4; ++q) {
        const int i0 = q * 1024 + t * 4;
        if (i0 >= nout) continue;
        const int p = PH(i0);
        if (i0 + 3 < nout) {
            *(float4*)(arp + i0) = make_float4(sre[p], sre[p+1], sre[p+2], sre[p+3]);
            *(float4*)(aip + i0) = make_float4(sim[p], sim[p+1], sim[p+2], sim[p+3]);
        } else {
            for (int k = 0; k < 4; ++k) if (i0 + k < nout) {
                arp[i0+k] = sre[p+k]; aip[i0+k] = sim[p+k];
            }
        }
    }
}

// ---------------- nonlinear conv + rotation ----------------
// Barrier-free per-wave staging + taps staged into wave-local LDS (round-12
// nl_rotate, the verified -14 µs/step lever): conv tap reads are uniform-
// address ds_read broadcasts. Conv FP chains identical to round 8.
#define K2_BLOCK 256
#define K2_TILE  2048
#define WOUT     512               // outputs per wave
#define K2_WLDSL 632               // per-wave logical window (512 + 120)
#define K2_WLDSP 720               // SWZ(631)=707, rounded to 16B multiple
#define NKTOT    (4 * NKP)         // 416 taps per b

#define N_CH8(W_, V_, N_, P0, P1, KK)                                      \
  {                                                                        \
    LD4V(N_[0],N_[1],N_[2],N_[3], sp[P0]);                                 \
    LD4V(N_[4],N_[5],N_[6],N_[7], sp[P1]);                                 \
    _Pragma("unroll")                                                      \
    for (int d = 0; d < 8; ++d) {                                          \
      const float av = nkA[(KK) + d], bv = nkB[(KK) + d];                  \
      _Pragma("unroll")                                                    \
      for (int j = 0; j < 8; ++j) {                                        \
        const float xv = (j + d < 8) ? W_[j + d] : V_[j + d - 8];          \
        th0[j] = fmaf(av, xv, th0[j]);                                     \
        th1[j] = fmaf(bv, xv, th1[j]);                                     \
      }                                                                    \
    }                                                                      \
  }

__global__ __launch_bounds__(K2_BLOCK, 4) void nl_rotate(
    const float* __restrict__ AR, const float* __restrict__ AI,
    const float* __restrict__ NKg, const float* __restrict__ COEF,
    float* __restrict__ XR, float* __restrict__ XI,
    float* __restrict__ OUT, int Lb, int finalstep)
{
    __shared__ __align__(16) float sw[4][2][K2_WLDSP];   // 23 KB
    __shared__ __align__(16) float snk[4][NKTOT];        // 6.5 KB (per-wave taps)
    const int b = blockIdx.y;
    const int tile0 = blockIdx.x * K2_TILE;
    const int nout  = min(K2_TILE, Lb - tile0);
    const int cnt   = nout + NTAPS_C - 1;
    const int w    = threadIdx.x >> 6;       // wave id 0..3
    const int lane = threadIdx.x & 63;
    const int wbase = w * WOUT;              // wave window start within tile
    const float* ar0 = AR + (size_t)(2 * b + 0) * SSTR + tile0;
    const float* ai0 = AI + (size_t)(2 * b + 0) * SSTR + tile0;
    const float* ar1 = AR + (size_t)(2 * b + 1) * SSTR + tile0;
    const float* ai1 = AI + (size_t)(2 * b + 1) * SSTR + tile0;

    float* sp0 = sw[w][0];
    float* sp1 = sw[w][1];
    float* stw = snk[w];

    // ---- per-wave tap staging: 416 floats = 104 float4 via 64 lanes ----
    {
        const float4* gsrc = (const float4*)(NKg + b * NKTOT);
        #pragma unroll
        for (int q = 0; q < 2; ++q) {
            const int i = q * 64 + lane;
            if (i < NKTOT / 4) ((float4*)stw)[i] = gsrc[i];
        }
    }

    // ---- per-wave staging: float4 loads, power, float4 LDS writes ----
    #pragma unroll
    for (int q = 0; q < 3; ++q) {
        const int i0 = q * 256 + lane * 4;   // local window index
        if (i0 < K2_WLDSL) {
            const int gi = wbase + i0;       // global-in-tile index
            float4 p0v = make_float4(0.f, 0.f, 0.f, 0.f);
            float4 p1v = make_float4(0.f, 0.f, 0.f, 0.f);
            if (gi + 3 < cnt) {
                float4 a4 = *(const float4*)(ar0 + gi);
                float4 c4 = *(const float4*)(ai0 + gi);
                float4 d4 = *(const float4*)(ar1 + gi);
                float4 e4 = *(const float4*)(ai1 + gi);
                p0v.x = fmaf(a4.x, a4.x, c4.x * c4.x);
                p0v.y = fmaf(a4.y, a4.y, c4.y * c4.y);
                p0v.z = fmaf(a4.z, a4.z, c4.z * c4.z);
                p0v.w = fmaf(a4.w, a4.w, c4.w * c4.w);
                p1v.x = fmaf(d4.x, d4.x, e4.x * e4.x);
                p1v.y = fmaf(d4.y, d4.y, e4.y * e4.y);
                p1v.z = fmaf(d4.z, d4.z, e4.z * e4.z);
                p1v.w = fmaf(d4.w, d4.w, e4.w * e4.w);
            } else {
                float p0a[4] = {0.f, 0.f, 0.f, 0.f};
                float p1a[4] = {0.f, 0.f, 0.f, 0.f};
                #pragma unroll
                for (int u = 0; u < 4; ++u) {
                    const int i = gi + u;
                    if (i < cnt) {
                        float a = ar0[i], c = ai0[i];
                        float d = ar1[i], e = ai1[i];
                        p0a[u] = fmaf(a, a, c * c);
                        p1a[u] = fmaf(d, d, e * e);
                    }
                }
                p0v = make_float4(p0a[0], p0a[1], p0a[2], p0a[3]);
                p1v = make_float4(p1a[0], p1a[1], p1a[2], p1a[3]);
            }
            const int p = SWZ(i0);   // i0%32 <= 28 -> 4 contiguous, 16B-aligned
            *(float4*)&sp0[p] = p0v;
            *(float4*)&sp1[p] = p1v;
        }
    }

    // ---- hoisted rotation operand loads (issue-early; drain under conv) ----
    const int t0 = wbase + lane * 8;         // global-in-tile output base
    const int lt0 = lane * 8;                // local-in-window output base
    float ra0[8], rb0[8], ra1[8], rb1[8];
    {
        const float* art0 = ar0 + t0 + NTAPS_C / 2;   // = AR[...][tg+50]
        const float* ait0 = ai0 + t0 + NTAPS_C / 2;
        const float* art1 = ar1 + t0 + NTAPS_C / 2;
        const float* ait1 = ai1 + t0 + NTAPS_C / 2;
        #pragma unroll
        for (int j = 0; j < 8; ++j) {
            ra0[j] = art0[j]; rb0[j] = ait0[j];
            ra1[j] = art1[j]; rb1[j] = ait1[j];
        }
    }

    // fence LDS writes -> reads within the wave (no block barrier needed;
    // all LDS data read below was written by this wave's own lanes)
    asm volatile("s_waitcnt lgkmcnt(0)" ::: "memory");
    __builtin_amdgcn_sched_barrier(0);

    if (t0 >= nout) return;

    float th0[8], th1[8];
    #pragma unroll
    for (int j = 0; j < 8; ++j) { th0[j] = 0.f; th1[j] = 0.f; }

    const int a0 = SWZ(lt0 + 16), a1 = SWZ(lt0 + 20), a2 = SWZ(lt0 + 24), a3 = SWZ(lt0 + 28);
    const int a4 = SWZ(lt0 + 32), a5 = SWZ(lt0 + 36), a6 = SWZ(lt0 + 40), a7 = SWZ(lt0 + 44);

    for (int im = 0; im < 2; ++im) {
        const float* sp  = im ? sp1 : sp0;
        const float* nkA = stw + (0 * 2 + im) * NKP;   // output mode 0 (LDS)
        const float* nkB = stw + (1 * 2 + im) * NKP;   // output mode 1 (LDS)
        float U[8], V[8], N[8];
        LD4V(U[0],U[1],U[2],U[3], sp[SWZ(lt0)]);
        LD4V(U[4],U[5],U[6],U[7], sp[SWZ(lt0 + 4)]);
        LD4V(V[0],V[1],V[2],V[3], sp[SWZ(lt0 + 8)]);
        LD4V(V[4],V[5],V[6],V[7], sp[SWZ(lt0 + 12)]);
        // 104 padded taps = 13 chunks (coeffs 101..103 are zero)
        N_CH8(U, V, N, a0,       a1,        0);
        N_CH8(V, N, U, a2,       a3,        8);
        N_CH8(N, U, V, a4,       a5,       16);
        N_CH8(U, V, N, a6,       a7,       24);
        N_CH8(V, N, U, a0 + 36,  a1 + 36,  32);
        N_CH8(N, U, V, a2 + 36,  a3 + 36,  40);
        N_CH8(U, V, N, a4 + 36,  a5 + 36,  48);
        N_CH8(V, N, U, a6 + 36,  a7 + 36,  56);
        N_CH8(N, U, V, a0 + 72,  a1 + 72,  64);
        N_CH8(U, V, N, a2 + 72,  a3 + 72,  72);
        N_CH8(V, N, U, a4 + 72,  a5 + 72,  80);
        N_CH8(N, U, V, a6 + 72,  a7 + 72,  88);
        N_CH8(U, V, N, a0 + 108, a1 + 108, 96);
    }

    const float coef = COEF[b];
    const int tg = tile0 + t0;

    float or0[8], oi0[8], or1[8], oi1[8];
    #pragma unroll
    for (int j = 0; j < 8; ++j) {
        float s0, c0, s1, c1;
        sincosf(th0[j] * coef, &s0, &c0);
        sincosf(th1[j] * coef, &s1, &c1);
        float a0v = ra0[j], b0v = rb0[j];
        float a1v = ra1[j], b1v = rb1[j];
        or0[j] = fmaf(a0v, c0, -b0v * s0);
        oi0[j] = fmaf(a0v, s0,  b0v * c0);
        or1[j] = fmaf(a1v, c1, -b1v * s1);
        oi1[j] = fmaf(a1v, s1,  b1v * c1);
    }

    const int rem = nout - t0;
    if (finalstep) {
        // out[b][t][c][ri] contiguous float4 per t
        float4* op = (float4*)(OUT + (size_t)(b * Lb + tg) * 4);
        if (rem >= 8) {
            #pragma unroll
            for (int j = 0; j < 8; ++j) op[j] = make_float4(or0[j], oi0[j], or1[j], oi1[j]);
        } else {
            for (int j = 0; j < rem; ++j) op[j] = make_float4(or0[j], oi0[j], or1[j], oi1[j]);
        }
    } else {
        float* xr0 = XR + (size_t)(2 * b + 0) * SSTR + tg;
        float* xi0 = XI + (size_t)(2 * b + 0) * SSTR + tg;
        float* xr1 = XR + (size_t)(2 * b + 1) * SSTR + tg;
        float* xi1 = XI + (size_t)(2 * b + 1) * SSTR + tg;
        if (rem >= 8) {
            ((float4*)xr0)[0] = make_float4(or0[0], or0[1], or0[2], or0[3]);
            ((float4*)xr0)[1] = make_float4(or0[4], or0[5], or0[6], or0[7]);
            ((float4*)xi0)[0] = make_float4(oi0[0], oi0[1], oi0[2], oi0[3]);
            ((float4*)xi0)[1] = make_float4(oi0[4], oi0[5], oi0[6], oi0[7]);
            ((float4*)xr1)[0] = make_float4(or1[0], or1[1], or1[2], or1[3]);
            ((float4*)xr1)[1] = make_float4(or1[4], or1[5], or1[6], or1[7]);
            ((float4*)xi1)[0] = make_float4(oi1[0], oi1[1], oi1[2], oi1[3]);
            ((float4*)xi1)[1] = make_float4(oi1[4], oi1[5], oi1[6], oi1[7]);
        } else {
            for (int j = 0; j < rem; ++j) {
                xr0[j] = or0[j]; xi0[j] = oi0[j];
                xr1[j] = or1[j]; xi1[j] = oi1[j];
            }
        }
    }
}

// ---------------- launch ----------------
extern "C" void kernel_launch(void* const* d_in, const int* in_sizes, int n_in,
                              void* d_out, int out_size, void* d_ws, size_t ws_size,
                              hipStream_t stream)
{
    const float* x_real = (const float*)d_in[0];
    const float* x_imag = (const float*)d_in[1];
    const float* task   = (const float*)d_in[2];
    const float* W1     = (const float*)d_in[3];
    const float* b1     = (const float*)d_in[4];
    const float* W2     = (const float*)d_in[5];
    const float* b2     = (const float*)d_in[6];
    float* out = (float*)d_out;
    float* ws  = (float*)d_ws;

    float* HR   = ws;
    float* HI   = HR + B_C * DTAPS_C;
    float* NKg  = HI + B_C * DTAPS_C;
    float* COEF = NKg + B_C * 4 * NKP;
    float* Gb   = ws + 16384;                       // B*4096 complex = 32768 f
    float* XR = ws + 16384 + 32768;
    float* XI = XR + (size_t)B_C * 2 * SEQ_C;
    float* AR = XI + (size_t)B_C * 2 * SEQ_C;
    float* AI = AR + (size_t)B_C * 2 * SEQ_C;

    build_disp<<<dim3(32, B_C), 256, 0, stream>>>(task, HR, HI);
    build_nk<<<1, 512, 0, stream>>>(task, W1, b1, W2, b2, NKg, COEF);
    build_G<<<dim3(128, B_C), 256, 0, stream>>>(HR, HI, Gb);
    {
        int n = B_C * SEQ_C;
        transpose_in<<<(n + 255) / 256, 256, 0, stream>>>(x_real, x_imag, XR, XI);
    }

    int L = SEQ_C;
    for (int s = 0; s < STEPS_C; ++s) {
        const int La = L - (DTAPS_C - 1);     // after dispersion FIR
        const int Lb = La - (NTAPS_C - 1);    // after nonlinear conv + trim
        dim3 g1((La + FSTEP - 1) / FSTEP, B_C * NM);
        disp_fft<<<g1, 256, 0, stream>>>(XR, XI, Gb, AR, AI, La);
        dim3 g2((Lb + K2_TILE - 1) / K2_TILE, B_C);
        nl_rotate<<<g2, K2_BLOCK, 0, stream>>>(AR, AI, NKg, COEF, XR, XI, out,
                                               Lb, (s == STEPS_C - 1) ? 1 : 0);
        L = Lb;
    }
}

// Round 14
// 323.463 us; speedup vs baseline: 1.0649x; 1.0649x over previous
//
#include <hip/hip_runtime.h>

// ---------------- problem constants ----------------
#define NM      2          // NMODES
#define STEPS_C 5
#define DTAPS_C 1001
#define NTAPS_C 101
#define HID_C   100
#define B_C     4
#define SEQ_C   500000
#define SSTR    SEQ_C      // per-(b,mode) stride in planar work buffers
#define NKP     104        // nonlinear taps padded to multiple of 8 (zeros)
#define FS_NOM_D 160000000000.0
#define PI_D 3.14159265358979323846

// LDS bank swizzle for nl_rotate: insert 4 pad floats every 32
#define SWZ(L) ((L) + ((((unsigned)(L)) >> 5) << 2))

#define LD4V(A0,A1,A2,A3, SRC) { float4 q_ = *(const float4*)&(SRC); \
    A0=q_.x; A1=q_.y; A2=q_.z; A3=q_.w; }

// complex multiply helper (outputs must not alias inputs)
__device__ __forceinline__ void cmulf(float& o_r, float& o_i,
                                      float a_r, float a_i, float b_r, float b_i)
{ o_r = a_r * b_r - a_i * b_i; o_i = a_r * b_i + a_i * b_r; }

// ---------------- dispersion kernel build (parallel DFT) ----------------
// grid (32, B), 256 thr. Block stages the 1001 freq-domain samples (fp64) in
// LDS; 32 outputs/block, 8-way k-split per output, shfl_xor reduce.
__global__ void build_disp(const float* __restrict__ task,
                           float* __restrict__ HR, float* __restrict__ HI)
{
    __shared__ double skr[DTAPS_C], ski[DTAPS_C];
    const int b = blockIdx.y;
    const double Fs = (double)task[b * 4 + 2];
    const double c_kms = 299792458.0 / 1000.0;
    const double Fc    = 299792458.0 / 1.55e-6;
    const double lamb  = c_kms / Fc;
    const double beta2 = -(16.5 * lamb * lamb) / (2.0 * PI_D * c_kms) / 1000.0;
    const double dz    = -400000.0;   // -(L_FIBER/STEP)

    for (int k = threadIdx.x; k < DTAPS_C; k += blockDim.x) {
        double fk = ((k <= DTAPS_C / 2) ? (double)k : (double)(k - DTAPS_C)) / (double)DTAPS_C;
        double om = 2.0 * PI_D * Fs * fk;
        double ph = 0.5 * beta2 * om * om * dz;
        ph = fmod(ph, 2.0 * PI_D);
        double s, c; sincos(ph, &s, &c);
        skr[k] = c;  ski[k] = -s;     // exp(-i*phase)
    }
    __syncthreads();

    const int ln = threadIdx.x >> 3;           // 0..31 output slot
    const int kp = threadIdx.x & 7;            // 0..7  k-part
    const int n  = blockIdx.x * 32 + ln;       // 0..1023
    double dr = 0.0, di = 0.0;
    {
        const int nn = (n < DTAPS_C) ? n : 0;
        // twiddle e^{+2pi i k n/1001}: start at k=kp, step 8
        const int r0 = (nn * kp) % DTAPS_C;
        const int rs = (nn * 8) % DTAPS_C;
        double a0 = 2.0 * PI_D * (double)r0 / (double)DTAPS_C;
        double as = 2.0 * PI_D * (double)rs / (double)DTAPS_C;
        double s0, c0, ss, cs;
        sincos(a0, &s0, &c0);
        sincos(as, &ss, &cs);
        for (int k = kp; k < DTAPS_C; k += 8) {
            dr += skr[k] * c0 - ski[k] * s0;
            di += skr[k] * s0 + ski[k] * c0;
            const double nc = c0 * cs - s0 * ss;
            s0 = c0 * ss + s0 * cs;
            c0 = nc;
        }
    }
    // reduce over kp (lanes differing in low 3 bits share one n)
    #pragma unroll
    for (int m = 1; m <= 4; m <<= 1) {
        dr += __shfl_xor(dr, m, 64);
        di += __shfl_xor(di, m, 64);
    }
    if (kp == 0 && n < DTAPS_C) {
        int m = n + DTAPS_C / 2; if (m >= DTAPS_C) m -= DTAPS_C;  // fftshift
        HR[b * DTAPS_C + m] = (float)(dr / (double)DTAPS_C);
        HI[b * DTAPS_C + m] = (float)(di / (double)DTAPS_C);
    }
}

// ---------------- filter spectrum for overlap-save FFT conv ----------------
// G[f] = (1/4096) * sum_k h[k] * e^{+2pi i f k / 4096}, stored at the
// digit-reversed (base-16, 3 digits) position so the FFT needs no reorder.
// grid (128, B), 256 thr: 32 outputs/block, 8-way k-split, shfl_xor reduce.
__global__ void build_G(const float* __restrict__ HR, const float* __restrict__ HI,
                        float* __restrict__ Gb)
{
    __shared__ float shr[DTAPS_C], shi[DTAPS_C];
    const int b = blockIdx.y;
    for (int k = threadIdx.x; k < DTAPS_C; k += blockDim.x) {
        shr[k] = HR[b * DTAPS_C + k];
        shi[k] = HI[b * DTAPS_C + k];
    }
    __syncthreads();

    const int ln = threadIdx.x >> 3;
    const int kp = threadIdx.x & 7;
    const int f  = blockIdx.x * 32 + ln;       // 0..4095
    double ar = 0.0, ai = 0.0;
    {
        // twiddle e^{+2pi i f k/4096}: start k=kp, step 8
        const int r0 = (f * kp) & 4095;
        const int rs = (f * 8) & 4095;
        double a0 = (2.0 * PI_D / 4096.0) * (double)r0;
        double as = (2.0 * PI_D / 4096.0) * (double)rs;
        double s0, c0, ss, cs;
        sincos(a0, &s0, &c0);
        sincos(as, &ss, &cs);
        for (int k = kp; k < DTAPS_C; k += 8) {
            const double hre = (double)shr[k], him = (double)shi[k];
            ar += hre * c0 - him * s0;
            ai += hre * s0 + him * c0;
            const double nc = c0 * cs - s0 * ss;
            s0 = c0 * ss + s0 * cs;
            c0 = nc;
        }
    }
    #pragma unroll
    for (int m = 1; m <= 4; m <<= 1) {
        ar += __shfl_xor(ar, m, 64);
        ai += __shfl_xor(ai, m, 64);
    }
    if (kp == 0) {
        const int p = ((f & 15) << 8) + (((f >> 4) & 15) << 4) + (f >> 8);
        Gb[(size_t)(b * 4096 + p) * 2 + 0] = (float)(ar * (1.0 / 4096.0));
        Gb[(size_t)(b * 4096 + p) * 2 + 1] = (float)(ai * (1.0 / 4096.0));
    }
}

// ---------------- nonlinear kernel build (tiny MLP) ----------------
__global__ void build_nk(const float* __restrict__ task,
                         const float* __restrict__ W1, const float* __restrict__ b1,
                         const float* __restrict__ W2, const float* __restrict__ b2,
                         float* __restrict__ NKg, float* __restrict__ COEF)
{
    const int tid = threadIdx.x;
    for (int i = tid; i < B_C * 4 * NKP; i += blockDim.x) NKg[i] = 0.f;
    if (tid < B_C) {
        float pdbm = task[tid * 4 + 0];
        float P = 0.001f * powf(10.f, pdbm * 0.1f) / (float)NM;
        COEF[tid] = (float)(0.0016567 * 400000.0) * P;  // GAMMA*DZ*P
    }
    __syncthreads();
    if (tid < B_C * NTAPS_C) {
        const int b = tid / NTAPS_C, tap = tid % NTAPS_C;
        float Fsn = task[b * 4 + 2] * (float)(1.0 / FS_NOM_D);
        float Ts = 1.f / Fsn, Ts2 = Ts * Ts;
        float pos = fabsf((float)(tap - NTAPS_C / 2)) * (1.f / 200.f);
        float inp = pos * Ts2;
        float o0 = b2[0], o1 = b2[1], o2 = b2[2], o3 = b2[3];
        for (int j = 0; j < HID_C; ++j) {
            float h = fmaxf(fmaf(inp, W1[j], b1[j]), 0.f);
            o0 = fmaf(h, W2[j * 4 + 0], o0);
            o1 = fmaf(h, W2[j * 4 + 1], o1);
            o2 = fmaf(h, W2[j * 4 + 2], o2);
            o3 = fmaf(h, W2[j * 4 + 3], o3);
        }
        float sc = Ts2 * expf(-pos * Ts2);
        NKg[(b * 4 + 0) * NKP + tap] = o0 * sc;
        NKg[(b * 4 + 1) * NKP + tap] = o1 * sc;
        NKg[(b * 4 + 2) * NKP + tap] = o2 * sc;
        NKg[(b * 4 + 3) * NKP + tap] = o3 * sc;
    }
}

// ---------------- input transpose (B,SEQ,2) -> planar (B,2,SEQ) -------------
__global__ void transpose_in(const float* __restrict__ xr_in, const float* __restrict__ xi_in,
                             float* __restrict__ XR, float* __restrict__ XI)
{
    int idx = blockIdx.x * blockDim.x + threadIdx.x;   // over B*SEQ
    if (idx >= B_C * SEQ_C) return;
    int b = idx / SEQ_C, t = idx - b * SEQ_C;
    float2 vr = ((const float2*)xr_in)[idx];
    float2 vi = ((const float2*)xi_in)[idx];
    XR[(size_t)(b * 2 + 0) * SSTR + t] = vr.x;
    XR[(size_t)(b * 2 + 1) * SSTR + t] = vr.y;
    XI[(size_t)(b * 2 + 0) * SSTR + t] = vi.x;
    XI[(size_t)(b * 2 + 1) * SSTR + t] = vi.y;
}

// ---------------- radix-16 building blocks (all-register, static idx) -------
template<int SGN>
__device__ __forceinline__ void dft4(float& ar, float& ai, float& br, float& bi,
                                     float& cr, float& ci, float& dr, float& di)
{
    float t0r = ar + cr, t0i = ai + ci;
    float t1r = ar - cr, t1i = ai - ci;
    float t2r = br + dr, t2i = bi + di;
    float t3r = br - dr, t3i = bi - di;
    ar = t0r + t2r; ai = t0i + t2i;          // y0
    cr = t0r - t2r; ci = t0i - t2i;          // y2
    if (SGN < 0) {                           // fwd: y1 = t1 - i t3, y3 = t1 + i t3
        br = t1r + t3i; bi = t1i - t3r;
        dr = t1r - t3i; di = t1i + t3r;
    } else {                                 // inv: conj
        br = t1r - t3i; bi = t1i + t3r;
        dr = t1r + t3i; di = t1i - t3r;
    }
}

template<int SGN>
__device__ __forceinline__ void tw16(float& r, float& i, float c, float s)
{
    // multiply by (c + SGN * i * s)
    float nr, ni;
    if (SGN < 0) { nr = r * c + i * s; ni = i * c - r * s; }
    else         { nr = r * c - i * s; ni = i * c + r * s; }
    r = nr; i = ni;
}

// In-place DFT16. Input x[m] at slot m; output X[k1+4k2] lands at slot 4*k1+k2
// i.e. X[k] at slot SIG(k) = 4*(k&3)+(k>>2) (an involution).
template<int SGN>
__device__ __forceinline__ void dft16(float (&xr)[16], float (&xi)[16])
{
    #pragma unroll
    for (int n1 = 0; n1 < 4; ++n1)
        dft4<SGN>(xr[n1], xi[n1], xr[n1+4], xi[n1+4],
                  xr[n1+8], xi[n1+8], xr[n1+12], xi[n1+12]);
    const float C1 = 0.923879532511286756f, S1 = 0.382683432365089772f;
    const float C2 = 0.707106781186547524f;
    tw16<SGN>(xr[5],  xi[5],  C1,  S1);      // w16^1
    tw16<SGN>(xr[9],  xi[9],  C2,  C2);      // w16^2
    tw16<SGN>(xr[13], xi[13], S1,  C1);      // w16^3
    tw16<SGN>(xr[6],  xi[6],  C2,  C2);      // w16^2
    tw16<SGN>(xr[10], xi[10], 0.f, 1.f);     // w16^4
    tw16<SGN>(xr[14], xi[14], -C2, C2);      // w16^6
    tw16<SGN>(xr[7],  xi[7],  S1,  C1);      // w16^3
    tw16<SGN>(xr[11], xi[11], -C2, C2);      // w16^6
    tw16<SGN>(xr[15], xi[15], -C1, -S1);     // w16^9
    #pragma unroll
    for (int k4 = 0; k4 < 4; ++k4)
        dft4<SGN>(xr[4*k4+0], xi[4*k4+0], xr[4*k4+1], xi[4*k4+1],
                  xr[4*k4+2], xi[4*k4+2], xr[4*k4+3], xi[4*k4+3]);
}

// Log-depth 16-twiddle ladder: given w = (c,s), derive w^2, w^3, w^4 once;
// tw_k = w^{4g} * w^{k&3}. Serial dependency depth ~5 complex mults instead
// of the 15-step recurrence (which throttled ILP in the store loops).
#define TWLADDER_INIT(c_, s_)                                              \
    float w1r_ = (c_), w1i_ = (s_), w2r_, w2i_, w3r_, w3i_, w4r_, w4i_;    \
    cmulf(w2r_, w2i_, w1r_, w1i_, w1r_, w1i_);                             \
    cmulf(w3r_, w3i_, w2r_, w2i_, w1r_, w1i_);                             \
    cmulf(w4r_, w4i_, w2r_, w2i_, w2r_, w2i_);                             \
    float bgr_ = 1.f, bgi_ = 0.f;

#define TWLADDER_GET(k_, twr_, twi_)                                       \
    {                                                                      \
        const int j_ = (k_) & 3;                                           \
        if      (j_ == 0) { twr_ = bgr_; twi_ = bgi_; }                    \
        else if (j_ == 1) cmulf(twr_, twi_, bgr_, bgi_, w1r_, w1i_);       \
        else if (j_ == 2) cmulf(twr_, twi_, bgr_, bgi_, w2r_, w2i_);       \
        else              cmulf(twr_, twi_, bgr_, bgi_, w3r_, w3i_);       \
    }

#define TWLADDER_STEP(k_)                                                  \
    if (((k_) & 3) == 3 && (k_) < 15) {                                    \
        float nr_, ni_;                                                    \
        cmulf(nr_, ni_, bgr_, bgi_, w4r_, w4i_);                           \
        bgr_ = nr_; bgi_ = ni_;                                            \
    }

// ---------------- dispersion via overlap-save FFT ----------------
// N=4096=16^3 complex FFT, 256 threads, one 16-pt DFT per thread per stage.
// Forward: 3 DIF radix-16 stages -> digit-reversed order; multiply by the
// pre-digit-reversed G; inverse: 3 DIT stages back to natural order.
// Fwd stage 3 + G-mult + inv stage 3 are fused in registers (no LDS pass).
// LDS pad: +2 floats per 32 -> stage-1/2 strided patterns are 2-way (free).
#define FFTN  4096
#define FSTEP 3096                 // valid outputs per segment (4096-1001+1)
#define PH(i) ((i) + ((((unsigned)(i)) >> 5) << 1))
#define LDSN  4352                 // PH(4095)=4349, rounded up

__global__ __launch_bounds__(256, 2) void disp_fft(
    const float* __restrict__ XR, const float* __restrict__ XI,
    const float* __restrict__ Gb,
    float* __restrict__ AR, float* __restrict__ AI, int La)
{
    __shared__ __align__(16) float sre[LDSN];
    __shared__ __align__(16) float sim[LDSN];
    const int t = threadIdx.x;
    const int seq = blockIdx.y;           // b*2 + mode
    const int b = seq >> 1;
    const int tile0 = blockIdx.x * FSTEP;
    const int Lin = La + (DTAPS_C - 1);   // current input length
    const int rem_in = Lin - tile0;       // >= 1001
    const float* xr = XR + (size_t)seq * SSTR + tile0;
    const float* xi = XI + (size_t)seq * SSTR + tile0;

    // ---- load segment (zero-padded tail) ----
    #pragma unroll
    for (int q = 0; q < 4; ++q) {
        const int i0 = q * 1024 + t * 4;
        float4 vr4 = make_float4(0.f, 0.f, 0.f, 0.f);
        float4 vi4 = make_float4(0.f, 0.f, 0.f, 0.f);
        if (i0 + 3 < rem_in) {
            vr4 = *(const float4*)(xr + i0);
            vi4 = *(const float4*)(xi + i0);
        } else {
            if (i0 + 0 < rem_in) { vr4.x = xr[i0+0]; vi4.x = xi[i0+0]; }
            if (i0 + 1 < rem_in) { vr4.y = xr[i0+1]; vi4.y = xi[i0+1]; }
            if (i0 + 2 < rem_in) { vr4.z = xr[i0+2]; vi4.z = xi[i0+2]; }
        }
        const int p = PH(i0);             // i0%32 <= 28 -> 4 contiguous
        sre[p+0] = vr4.x; sre[p+1] = vr4.y; sre[p+2] = vr4.z; sre[p+3] = vr4.w;
        sim[p+0] = vi4.x; sim[p+1] = vi4.y; sim[p+2] = vi4.z; sim[p+3] = vi4.w;
    }
    __syncthreads();

    float vr[16], vi[16];

    // ---- FWD stage 1: L=4096, j=t, addr = t + 256*m -> PH = PH(t) + 272*m
    {
        const int base = PH(t);
        #pragma unroll
        for (int m = 0; m < 16; ++m) { vr[m] = sre[base + 272*m]; vi[m] = sim[base + 272*m]; }
        dft16<-1>(vr, vi);
        float s, c; sincosf((float)(-2.0 * PI_D / 4096.0) * (float)t, &s, &c);
        TWLADDER_INIT(c, s)
        #pragma unroll
        for (int k = 0; k < 16; ++k) {
            const int sl = 4*(k&3) + (k>>2);
            float twr, twi;
            TWLADDER_GET(k, twr, twi)
            sre[base + 272*k] = vr[sl]*twr - vi[sl]*twi;
            sim[base + 272*k] = vr[sl]*twi + vi[sl]*twr;
            TWLADDER_STEP(k)
        }
    }
    __syncthreads();

    // ---- FWD stage 2: L=256, blk=t>>4, j=t&15, addr = 256blk + j + 16m
    {
        const int j = t & 15, blk = t >> 4;
        const int base = 272*blk + j;
        #pragma unroll
        for (int m = 0; m < 16; ++m) {
            const int o = base + 16*m + 2*(m>>1);
            vr[m] = sre[o]; vi[m] = sim[o];
        }
        dft16<-1>(vr, vi);
        float s, c; sincosf((float)(-2.0 * PI_D / 256.0) * (float)j, &s, &c);
        TWLADDER_INIT(c, s)
        #pragma unroll
        for (int k = 0; k < 16; ++k) {
            const int sl = 4*(k&3) + (k>>2);
            const int o = base + 16*k + 2*(k>>1);
            float twr, twi;
            TWLADDER_GET(k, twr, twi)
            sre[o] = vr[sl]*twr - vi[sl]*twi;
            sim[o] = vr[sl]*twi + vi[sl]*twr;
            TWLADDER_STEP(k)
        }
    }
    __syncthreads();

    // ---- fused: FWD stage 3 (contig 16, no twiddle) + G multiply + INV stage 3
    {
        const int base = 16*t + 2*(t>>1);    // PH(16t + m) = base + m
        #pragma unroll
        for (int m = 0; m < 16; ++m) { vr[m] = sre[base + m]; vi[m] = sim[base + m]; }
        dft16<-1>(vr, vi);
        const float2* gp = ((const float2*)Gb) + ((size_t)b << 12) + (t << 4);
        float wr2[16], wi2[16];
        #pragma unroll
        for (int k = 0; k < 16; ++k) {
            const int sl = 4*(k&3) + (k>>2);
            const float2 g = gp[k];          // G at digit-reversed pos 16t+k
            wr2[k] = vr[sl]*g.x - vi[sl]*g.y;
            wi2[k] = vr[sl]*g.y + vi[sl]*g.x;
        }
        dft16<1>(wr2, wi2);
        #pragma unroll
        for (int m = 0; m < 16; ++m) {
            const int sl = 4*(m&3) + (m>>2);
            sre[base + m] = wr2[sl]; sim[base + m] = wi2[sl];
        }
    }
    __syncthreads();

    // ---- INV stage 2': conj twiddle on input, iDFT16, write to m-slots
    {
        const int j = t & 15, blk = t >> 4;
        const int base = 272*blk + j;
        float s, c; sincosf((float)(2.0 * PI_D / 256.0) * (float)j, &s, &c);
        TWLADDER_INIT(c, s)
        #pragma unroll
        for (int k = 0; k < 16; ++k) {
            const int o = base + 16*k + 2*(k>>1);
            const float a = sre[o], d = sim[o];
            float twr, twi;
            TWLADDER_GET(k, twr, twi)
            vr[k] = a*twr - d*twi; vi[k] = a*twi + d*twr;
            TWLADDER_STEP(k)
        }
        dft16<1>(vr, vi);
        #pragma unroll
        for (int m = 0; m < 16; ++m) {
            const int sl = 4*(m&3) + (m>>2);
            const int o = base + 16*m + 2*(m>>1);
            sre[o] = vr[sl]; sim[o] = vi[sl];
        }
    }
    __syncthreads();

    // ---- INV stage 1'
    {
        const int base = PH(t);
        float s, c; sincosf((float)(2.0 * PI_D / 4096.0) * (float)t, &s, &c);
        TWLADDER_INIT(c, s)
        #pragma unroll
        for (int k = 0; k < 16; ++k) {
            const float a = sre[base + 272*k], d = sim[base + 272*k];
            float twr, twi;
            TWLADDER_GET(k, twr, twi)
            vr[k] = a*twr - d*twi; vi[k] = a*twi + d*twr;
            TWLADDER_STEP(k)
        }
        dft16<1>(vr, vi);
        #pragma unroll
        for (int m = 0; m < 16; ++m) {
            const int sl = 4*(m&3) + (m>>2);
            sre[base + 272*m] = vr[sl]; sim[base + 272*m] = vi[sl];
        }
    }
    __syncthreads();

    // ---- store valid outputs [0, nout) ----
    const int nout = min(FSTEP, La - tile0);
    float* arp = AR + (size_t)seq * SSTR + tile0;
    float* aip = AI + (size_t)seq * SSTR + tile0;
    #pragma unroll
    for (int q = 0; q < 4; ++q) {
        const int i0 = q * 1024 + t * 4;
        if (i0 >= nout) continue;
        const int p = PH(i0);
        if (i0 + 3 < nout) {
            *(float4*)(arp + i0) = make_float4(sre[p], sre[p+1], sre[p+2], sre[p+3]);
            *(float4*)(aip + i0) = make_float4(sim[p], sim[p+1], sim[p+2], sim[p+3]);
        } else {
            for (int k = 0; k < 4; ++k) if (i0 + k < nout) {
                arp[i0+k] = sre[p+k]; aip[i0+k] = sim[p+k];
            }
        }
    }
}

// ---------------- nonlinear conv + rotation ----------------
// BARRIER-FREE per-wave staging: each of the 4 waves owns 512 outputs and
// stages its own 632-float power window (512 + 120 halo) into private LDS.
// Reads only hit the owning wave's writes -> no __syncthreads; an explicit
// lgkmcnt(0) + sched_barrier fences LDS write->read within the wave. Waves
// run fully independently, so staging latency of one wave hides under the
// conv of another. Conv FP chains identical to the verified round-8 kernel.
#define K2_BLOCK 256
#define K2_TILE  2048
#define WOUT     512               // outputs per wave
#define K2_WLDSL 632               // per-wave logical window (512 + 120)
#define K2_WLDSP 720               // SWZ(631)=707, rounded to 16B multiple

#define N_CH8(W_, V_, N_, P0, P1, KK)                                      \
  {                                                                        \
    LD4V(N_[0],N_[1],N_[2],N_[3], sp[P0]);                                 \
    LD4V(N_[4],N_[5],N_[6],N_[7], sp[P1]);                                 \
    _Pragma("unroll")                                                      \
    for (int d = 0; d < 8; ++d) {                                          \
      const float av = nkA[(KK) + d], bv = nkB[(KK) + d];                  \
      _Pragma("unroll")                                                    \
      for (int j = 0; j < 8; ++j) {                                        \
        const float xv = (j + d < 8) ? W_[j + d] : V_[j + d - 8];          \
        th0[j] = fmaf(av, xv, th0[j]);                                     \
        th1[j] = fmaf(bv, xv, th1[j]);                                     \
      }                                                                    \
    }                                                                      \
  }

__global__ __launch_bounds__(K2_BLOCK, 4) void nl_rotate(
    const float* __restrict__ AR, const float* __restrict__ AI,
    const float* __restrict__ NKg, const float* __restrict__ COEF,
    float* __restrict__ XR, float* __restrict__ XI,
    float* __restrict__ OUT, int Lb, int finalstep)
{
    __shared__ __align__(16) float sw[4][2][K2_WLDSP];   // 23 KB
    const int b = blockIdx.y;
    const int tile0 = blockIdx.x * K2_TILE;
    const int nout  = min(K2_TILE, Lb - tile0);
    const int cnt   = nout + NTAPS_C - 1;
    const int w    = threadIdx.x >> 6;       // wave id 0..3
    const int lane = threadIdx.x & 63;
    const int wbase = w * WOUT;              // wave window start within tile
    const float* ar0 = AR + (size_t)(2 * b + 0) * SSTR + tile0;
    const float* ai0 = AI + (size_t)(2 * b + 0) * SSTR + tile0;
    const float* ar1 = AR + (size_t)(2 * b + 1) * SSTR + tile0;
    const float* ai1 = AI + (size_t)(2 * b + 1) * SSTR + tile0;

    float* sp0 = sw[w][0];
    float* sp1 = sw[w][1];

    // ---- per-wave staging: float4 loads, power, float4 LDS writes ----
    #pragma unroll
    for (int q = 0; q < 3; ++q) {
        const int i0 = q * 256 + lane * 4;   // local window index
        if (i0 < K2_WLDSL) {
            const int gi = wbase + i0;       // global-in-tile index
            float4 p0v = make_float4(0.f, 0.f, 0.f, 0.f);
            float4 p1v = make_float4(0.f, 0.f, 0.f, 0.f);
            if (gi + 3 < cnt) {
                float4 a4 = *(const float4*)(ar0 + gi);
                float4 c4 = *(const float4*)(ai0 + gi);
                float4 d4 = *(const float4*)(ar1 + gi);
                float4 e4 = *(const float4*)(ai1 + gi);
                p0v.x = fmaf(a4.x, a4.x, c4.x * c4.x);
                p0v.y = fmaf(a4.y, a4.y, c4.y * c4.y);
                p0v.z = fmaf(a4.z, a4.z, c4.z * c4.z);
                p0v.w = fmaf(a4.w, a4.w, c4.w * c4.w);
                p1v.x = fmaf(d4.x, d4.x, e4.x * e4.x);
                p1v.y = fmaf(d4.y, d4.y, e4.y * e4.y);
                p1v.z = fmaf(d4.z, d4.z, e4.z * e4.z);
                p1v.w = fmaf(d4.w, d4.w, e4.w * e4.w);
            } else {
                float p0a[4] = {0.f, 0.f, 0.f, 0.f};
                float p1a[4] = {0.f, 0.f, 0.f, 0.f};
                #pragma unroll
                for (int u = 0; u < 4; ++u) {
                    const int i = gi + u;
                    if (i < cnt) {
                        float a = ar0[i], c = ai0[i];
                        float d = ar1[i], e = ai1[i];
                        p0a[u] = fmaf(a, a, c * c);
                        p1a[u] = fmaf(d, d, e * e);
                    }
                }
                p0v = make_float4(p0a[0], p0a[1], p0a[2], p0a[3]);
                p1v = make_float4(p1a[0], p1a[1], p1a[2], p1a[3]);
            }
            const int p = SWZ(i0);   // i0%32 <= 28 -> 4 contiguous, 16B-aligned
            *(float4*)&sp0[p] = p0v;
            *(float4*)&sp1[p] = p1v;
        }
    }

    // ---- hoisted rotation operand loads (issue-early; drain under conv) ----
    const int t0 = wbase + lane * 8;         // global-in-tile output base
    const int lt0 = lane * 8;                // local-in-window output base
    float ra0[8], rb0[8], ra1[8], rb1[8];
    {
        const float* art0 = ar0 + t0 + NTAPS_C / 2;   // = AR[...][tg+50]
        const float* ait0 = ai0 + t0 + NTAPS_C / 2;
        const float* art1 = ar1 + t0 + NTAPS_C / 2;
        const float* ait1 = ai1 + t0 + NTAPS_C / 2;
        #pragma unroll
        for (int j = 0; j < 8; ++j) {
            ra0[j] = art0[j]; rb0[j] = ait0[j];
            ra1[j] = art1[j]; rb1[j] = ait1[j];
        }
    }

    // fence LDS writes -> reads within the wave (no block barrier needed)
    asm volatile("s_waitcnt lgkmcnt(0)" ::: "memory");
    __builtin_amdgcn_sched_barrier(0);

    if (t0 >= nout) return;

    float th0[8], th1[8];
    #pragma unroll
    for (int j = 0; j < 8; ++j) { th0[j] = 0.f; th1[j] = 0.f; }
    const float* nkb = NKg + b * 4 * NKP;

    const int a0 = SWZ(lt0 + 16), a1 = SWZ(lt0 + 20), a2 = SWZ(lt0 + 24), a3 = SWZ(lt0 + 28);
    const int a4 = SWZ(lt0 + 32), a5 = SWZ(lt0 + 36), a6 = SWZ(lt0 + 40), a7 = SWZ(lt0 + 44);

    for (int im = 0; im < 2; ++im) {
        const float* sp  = im ? sp1 : sp0;
        const float* nkA = nkb + (0 * 2 + im) * NKP;   // output mode 0
        const float* nkB = nkb + (1 * 2 + im) * NKP;   // output mode 1
        float U[8], V[8], N[8];
        LD4V(U[0],U[1],U[2],U[3], sp[SWZ(lt0)]);
        LD4V(U[4],U[5],U[6],U[7], sp[SWZ(lt0 + 4)]);
        LD4V(V[0],V[1],V[2],V[3], sp[SWZ(lt0 + 8)]);
        LD4V(V[4],V[5],V[6],V[7], sp[SWZ(lt0 + 12)]);
        // 104 padded taps = 13 chunks (coeffs 101..103 are zero)
        N_CH8(U, V, N, a0,       a1,        0);
        N_CH8(V, N, U, a2,       a3,        8);
        N_CH8(N, U, V, a4,       a5,       16);
        N_CH8(U, V, N, a6,       a7,       24);
        N_CH8(V, N, U, a0 + 36,  a1 + 36,  32);
        N_CH8(N, U, V, a2 + 36,  a3 + 36,  40);
        N_CH8(U, V, N, a4 + 36,  a5 + 36,  48);
        N_CH8(V, N, U, a6 + 36,  a7 + 36,  56);
        N_CH8(N, U, V, a0 + 72,  a1 + 72,  64);
        N_CH8(U, V, N, a2 + 72,  a3 + 72,  72);
        N_CH8(V, N, U, a4 + 72,  a5 + 72,  80);
        N_CH8(N, U, V, a6 + 72,  a7 + 72,  88);
        N_CH8(U, V, N, a0 + 108, a1 + 108, 96);
    }

    const float coef = COEF[b];
    const int tg = tile0 + t0;

    float or0[8], oi0[8], or1[8], oi1[8];
    #pragma unroll
    for (int j = 0; j < 8; ++j) {
        float s0, c0, s1, c1;
        sincosf(th0[j] * coef, &s0, &c0);
        sincosf(th1[j] * coef, &s1, &c1);
        float a0v = ra0[j], b0v = rb0[j];
        float a1v = ra1[j], b1v = rb1[j];
        or0[j] = fmaf(a0v, c0, -b0v * s0);
        oi0[j] = fmaf(a0v, s0,  b0v * c0);
        or1[j] = fmaf(a1v, c1, -b1v * s1);
        oi1[j] = fmaf(a1v, s1,  b1v * c1);
    }

    const int rem = nout - t0;
    if (finalstep) {
        // out[b][t][c][ri] contiguous float4 per t
        float4* op = (float4*)(OUT + (size_t)(b * Lb + tg) * 4);
        if (rem >= 8) {
            #pragma unroll
            for (int j = 0; j < 8; ++j) op[j] = make_float4(or0[j], oi0[j], or1[j], oi1[j]);
        } else {
            for (int j = 0; j < rem; ++j) op[j] = make_float4(or0[j], oi0[j], or1[j], oi1[j]);
        }
    } else {
        float* xr0 = XR + (size_t)(2 * b + 0) * SSTR + tg;
        float* xi0 = XI + (size_t)(2 * b + 0) * SSTR + tg;
        float* xr1 = XR + (size_t)(2 * b + 1) * SSTR + tg;
        float* xi1 = XI + (size_t)(2 * b + 1) * SSTR + tg;
        if (rem >= 8) {
            ((float4*)xr0)[0] = make_float4(or0[0], or0[1], or0[2], or0[3]);
            ((float4*)xr0)[1] = make_float4(or0[4], or0[5], or0[6], or0[7]);
            ((float4*)xi0)[0] = make_float4(oi0[0], oi0[1], oi0[2], oi0[3]);
            ((float4*)xi0)[1] = make_float4(oi0[4], oi0[5], oi0[6], oi0[7]);
            ((float4*)xr1)[0] = make_float4(or1[0], or1[1], or1[2], or1[3]);
            ((float4*)xr1)[1] = make_float4(or1[4], or1[5], or1[6], or1[7]);
            ((float4*)xi1)[0] = make_float4(oi1[0], oi1[1], oi1[2], oi1[3]);
            ((float4*)xi1)[1] = make_float4(oi1[4], oi1[5], oi1[6], oi1[7]);
        } else {
            for (int j = 0; j < rem; ++j) {
                xr0[j] = or0[j]; xi0[j] = oi0[j];
                xr1[j] = or1[j]; xi1[j] = oi1[j];
            }
        }
    }
}

// ---------------- launch ----------------
extern "C" void kernel_launch(void* const* d_in, const int* in_sizes, int n_in,
                              void* d_out, int out_size, void* d_ws, size_t ws_size,
                              hipStream_t stream)
{
    const float* x_real = (const float*)d_in[0];
    const float* x_imag = (const float*)d_in[1];
    const float* task   = (const float*)d_in[2];
    const float* W1     = (const float*)d_in[3];
    const float* b1     = (const float*)d_in[4];
    const float* W2     = (const float*)d_in[5];
    const float* b2     = (const float*)d_in[6];
    float* out = (float*)d_out;
    float* ws  = (float*)d_ws;

    float* HR   = ws;
    float* HI   = HR + B_C * DTAPS_C;
    float* NKg  = HI + B_C * DTAPS_C;
    float* COEF = NKg + B_C * 4 * NKP;
    float* Gb   = ws + 16384;                       // B*4096 complex = 32768 f
    float* XR = ws + 16384 + 32768;
    float* XI = XR + (size_t)B_C * 2 * SEQ_C;
    float* AR = XI + (size_t)B_C * 2 * SEQ_C;
    float* AI = AR + (size_t)B_C * 2 * SEQ_C;

    build_disp<<<dim3(32, B_C), 256, 0, stream>>>(task, HR, HI);
    build_nk<<<1, 512, 0, stream>>>(task, W1, b1, W2, b2, NKg, COEF);
    build_G<<<dim3(128, B_C), 256, 0, stream>>>(HR, HI, Gb);
    {
        int n = B_C * SEQ_C;
        transpose_in<<<(n + 255) / 256, 256, 0, stream>>>(x_real, x_imag, XR, XI);
    }

    int L = SEQ_C;
    for (int s = 0; s < STEPS_C; ++s) {
        const int La = L - (DTAPS_C - 1);     // after dispersion FIR
        const int Lb = La - (NTAPS_C - 1);    // after nonlinear conv + trim
        dim3 g1((La + FSTEP - 1) / FSTEP, B_C * NM);
        disp_fft<<<g1, 256, 0, stream>>>(XR, XI, Gb, AR, AI, La);
        dim3 g2((Lb + K2_TILE - 1) / K2_TILE, B_C);
        nl_rotate<<<g2, K2_BLOCK, 0, stream>>>(AR, AI, NKg, COEF, XR, XI, out,
                                               Lb, (s == STEPS_C - 1) ? 1 : 0);
        L = Lb;
    }
}

// Round 15
// 308.512 us; speedup vs baseline: 1.1165x; 1.0485x over previous
//
#include <hip/hip_runtime.h>

// ---------------- problem constants ----------------
#define NM      2          // NMODES
#define STEPS_C 5
#define DTAPS_C 1001
#define NTAPS_C 101
#define HID_C   100
#define B_C     4
#define SEQ_C   500000
#define SSTR    SEQ_C      // per-(b,mode) stride in planar work buffers
#define NKP     104        // nonlinear taps padded to multiple of 8 (zeros)
#define FS_NOM_D 160000000000.0
#define PI_D 3.14159265358979323846

// LDS bank swizzle for nl_rotate: insert 4 pad floats every 32
#define SWZ(L) ((L) + ((((unsigned)(L)) >> 5) << 2))

#define LD4V(A0,A1,A2,A3, SRC) { float4 q_ = *(const float4*)&(SRC); \
    A0=q_.x; A1=q_.y; A2=q_.z; A3=q_.w; }

// complex multiply helper (outputs must not alias inputs)
__device__ __forceinline__ void cmulf(float& o_r, float& o_i,
                                      float a_r, float a_i, float b_r, float b_i)
{ o_r = a_r * b_r - a_i * b_i; o_i = a_r * b_i + a_i * b_r; }

// ---------------- dispersion kernel build (parallel DFT) ----------------
// grid (32, B), 256 thr. Block stages the 1001 freq-domain samples (fp64) in
// LDS; 32 outputs/block, 8-way k-split per output, shfl_xor reduce.
__global__ void build_disp(const float* __restrict__ task,
                           float* __restrict__ HR, float* __restrict__ HI)
{
    __shared__ double skr[DTAPS_C], ski[DTAPS_C];
    const int b = blockIdx.y;
    const double Fs = (double)task[b * 4 + 2];
    const double c_kms = 299792458.0 / 1000.0;
    const double Fc    = 299792458.0 / 1.55e-6;
    const double lamb  = c_kms / Fc;
    const double beta2 = -(16.5 * lamb * lamb) / (2.0 * PI_D * c_kms) / 1000.0;
    const double dz    = -400000.0;   // -(L_FIBER/STEP)

    for (int k = threadIdx.x; k < DTAPS_C; k += blockDim.x) {
        double fk = ((k <= DTAPS_C / 2) ? (double)k : (double)(k - DTAPS_C)) / (double)DTAPS_C;
        double om = 2.0 * PI_D * Fs * fk;
        double ph = 0.5 * beta2 * om * om * dz;
        ph = fmod(ph, 2.0 * PI_D);
        double s, c; sincos(ph, &s, &c);
        skr[k] = c;  ski[k] = -s;     // exp(-i*phase)
    }
    __syncthreads();

    const int ln = threadIdx.x >> 3;           // 0..31 output slot
    const int kp = threadIdx.x & 7;            // 0..7  k-part
    const int n  = blockIdx.x * 32 + ln;       // 0..1023
    double dr = 0.0, di = 0.0;
    {
        const int nn = (n < DTAPS_C) ? n : 0;
        // twiddle e^{+2pi i k n/1001}: start at k=kp, step 8
        const int r0 = (nn * kp) % DTAPS_C;
        const int rs = (nn * 8) % DTAPS_C;
        double a0 = 2.0 * PI_D * (double)r0 / (double)DTAPS_C;
        double as = 2.0 * PI_D * (double)rs / (double)DTAPS_C;
        double s0, c0, ss, cs;
        sincos(a0, &s0, &c0);
        sincos(as, &ss, &cs);
        for (int k = kp; k < DTAPS_C; k += 8) {
            dr += skr[k] * c0 - ski[k] * s0;
            di += skr[k] * s0 + ski[k] * c0;
            const double nc = c0 * cs - s0 * ss;
            s0 = c0 * ss + s0 * cs;
            c0 = nc;
        }
    }
    // reduce over kp (lanes differing in low 3 bits share one n)
    #pragma unroll
    for (int m = 1; m <= 4; m <<= 1) {
        dr += __shfl_xor(dr, m, 64);
        di += __shfl_xor(di, m, 64);
    }
    if (kp == 0 && n < DTAPS_C) {
        int m = n + DTAPS_C / 2; if (m >= DTAPS_C) m -= DTAPS_C;  // fftshift
        HR[b * DTAPS_C + m] = (float)(dr / (double)DTAPS_C);
        HI[b * DTAPS_C + m] = (float)(di / (double)DTAPS_C);
    }
}

// ---------------- filter spectrum for overlap-save FFT conv ----------------
// G[f] = (1/4096) * sum_k h[k] * e^{+2pi i f k / 4096}, stored at the
// digit-reversed (base-16, 3 digits) position so the FFT needs no reorder.
// grid (128, B), 256 thr: 32 outputs/block, 8-way k-split, shfl_xor reduce.
__global__ void build_G(const float* __restrict__ HR, const float* __restrict__ HI,
                        float* __restrict__ Gb)
{
    __shared__ float shr[DTAPS_C], shi[DTAPS_C];
    const int b = blockIdx.y;
    for (int k = threadIdx.x; k < DTAPS_C; k += blockDim.x) {
        shr[k] = HR[b * DTAPS_C + k];
        shi[k] = HI[b * DTAPS_C + k];
    }
    __syncthreads();

    const int ln = threadIdx.x >> 3;
    const int kp = threadIdx.x & 7;
    const int f  = blockIdx.x * 32 + ln;       // 0..4095
    double ar = 0.0, ai = 0.0;
    {
        // twiddle e^{+2pi i f k/4096}: start k=kp, step 8
        const int r0 = (f * kp) & 4095;
        const int rs = (f * 8) & 4095;
        double a0 = (2.0 * PI_D / 4096.0) * (double)r0;
        double as = (2.0 * PI_D / 4096.0) * (double)rs;
        double s0, c0, ss, cs;
        sincos(a0, &s0, &c0);
        sincos(as, &ss, &cs);
        for (int k = kp; k < DTAPS_C; k += 8) {
            const double hre = (double)shr[k], him = (double)shi[k];
            ar += hre * c0 - him * s0;
            ai += hre * s0 + him * c0;
            const double nc = c0 * cs - s0 * ss;
            s0 = c0 * ss + s0 * cs;
            c0 = nc;
        }
    }
    #pragma unroll
    for (int m = 1; m <= 4; m <<= 1) {
        ar += __shfl_xor(ar, m, 64);
        ai += __shfl_xor(ai, m, 64);
    }
    if (kp == 0) {
        const int p = ((f & 15) << 8) + (((f >> 4) & 15) << 4) + (f >> 8);
        Gb[(size_t)(b * 4096 + p) * 2 + 0] = (float)(ar * (1.0 / 4096.0));
        Gb[(size_t)(b * 4096 + p) * 2 + 1] = (float)(ai * (1.0 / 4096.0));
    }
}

// ---------------- nonlinear kernel build (tiny MLP) ----------------
__global__ void build_nk(const float* __restrict__ task,
                         const float* __restrict__ W1, const float* __restrict__ b1,
                         const float* __restrict__ W2, const float* __restrict__ b2,
                         float* __restrict__ NKg, float* __restrict__ COEF)
{
    const int tid = threadIdx.x;
    for (int i = tid; i < B_C * 4 * NKP; i += blockDim.x) NKg[i] = 0.f;
    if (tid < B_C) {
        float pdbm = task[tid * 4 + 0];
        float P = 0.001f * powf(10.f, pdbm * 0.1f) / (float)NM;
        COEF[tid] = (float)(0.0016567 * 400000.0) * P;  // GAMMA*DZ*P
    }
    __syncthreads();
    if (tid < B_C * NTAPS_C) {
        const int b = tid / NTAPS_C, tap = tid % NTAPS_C;
        float Fsn = task[b * 4 + 2] * (float)(1.0 / FS_NOM_D);
        float Ts = 1.f / Fsn, Ts2 = Ts * Ts;
        float pos = fabsf((float)(tap - NTAPS_C / 2)) * (1.f / 200.f);
        float inp = pos * Ts2;
        float o0 = b2[0], o1 = b2[1], o2 = b2[2], o3 = b2[3];
        for (int j = 0; j < HID_C; ++j) {
            float h = fmaxf(fmaf(inp, W1[j], b1[j]), 0.f);
            o0 = fmaf(h, W2[j * 4 + 0], o0);
            o1 = fmaf(h, W2[j * 4 + 1], o1);
            o2 = fmaf(h, W2[j * 4 + 2], o2);
            o3 = fmaf(h, W2[j * 4 + 3], o3);
        }
        float sc = Ts2 * expf(-pos * Ts2);
        NKg[(b * 4 + 0) * NKP + tap] = o0 * sc;
        NKg[(b * 4 + 1) * NKP + tap] = o1 * sc;
        NKg[(b * 4 + 2) * NKP + tap] = o2 * sc;
        NKg[(b * 4 + 3) * NKP + tap] = o3 * sc;
    }
}

// ---------------- input transpose (B,SEQ,2) -> planar (B,2,SEQ) -------------
__global__ void transpose_in(const float* __restrict__ xr_in, const float* __restrict__ xi_in,
                             float* __restrict__ XR, float* __restrict__ XI)
{
    int idx = blockIdx.x * blockDim.x + threadIdx.x;   // over B*SEQ
    if (idx >= B_C * SEQ_C) return;
    int b = idx / SEQ_C, t = idx - b * SEQ_C;
    float2 vr = ((const float2*)xr_in)[idx];
    float2 vi = ((const float2*)xi_in)[idx];
    XR[(size_t)(b * 2 + 0) * SSTR + t] = vr.x;
    XR[(size_t)(b * 2 + 1) * SSTR + t] = vr.y;
    XI[(size_t)(b * 2 + 0) * SSTR + t] = vi.x;
    XI[(size_t)(b * 2 + 1) * SSTR + t] = vi.y;
}

// ---------------- radix-16 building blocks (all-register, static idx) -------
template<int SGN>
__device__ __forceinline__ void dft4(float& ar, float& ai, float& br, float& bi,
                                     float& cr, float& ci, float& dr, float& di)
{
    float t0r = ar + cr, t0i = ai + ci;
    float t1r = ar - cr, t1i = ai - ci;
    float t2r = br + dr, t2i = bi + di;
    float t3r = br - dr, t3i = bi - di;
    ar = t0r + t2r; ai = t0i + t2i;          // y0
    cr = t0r - t2r; ci = t0i - t2i;          // y2
    if (SGN < 0) {                           // fwd: y1 = t1 - i t3, y3 = t1 + i t3
        br = t1r + t3i; bi = t1i - t3r;
        dr = t1r - t3i; di = t1i + t3r;
    } else {                                 // inv: conj
        br = t1r - t3i; bi = t1i + t3r;
        dr = t1r + t3i; di = t1i - t3r;
    }
}

template<int SGN>
__device__ __forceinline__ void tw16(float& r, float& i, float c, float s)
{
    // multiply by (c + SGN * i * s)
    float nr, ni;
    if (SGN < 0) { nr = r * c + i * s; ni = i * c - r * s; }
    else         { nr = r * c - i * s; ni = i * c + r * s; }
    r = nr; i = ni;
}

// In-place DFT16. Input x[m] at slot m; output X[k1+4k2] lands at slot 4*k1+k2
// i.e. X[k] at slot SIG(k) = 4*(k&3)+(k>>2) (an involution).
template<int SGN>
__device__ __forceinline__ void dft16(float (&xr)[16], float (&xi)[16])
{
    #pragma unroll
    for (int n1 = 0; n1 < 4; ++n1)
        dft4<SGN>(xr[n1], xi[n1], xr[n1+4], xi[n1+4],
                  xr[n1+8], xi[n1+8], xr[n1+12], xi[n1+12]);
    const float C1 = 0.923879532511286756f, S1 = 0.382683432365089772f;
    const float C2 = 0.707106781186547524f;
    tw16<SGN>(xr[5],  xi[5],  C1,  S1);      // w16^1
    tw16<SGN>(xr[9],  xi[9],  C2,  C2);      // w16^2
    tw16<SGN>(xr[13], xi[13], S1,  C1);      // w16^3
    tw16<SGN>(xr[6],  xi[6],  C2,  C2);      // w16^2
    tw16<SGN>(xr[10], xi[10], 0.f, 1.f);     // w16^4
    tw16<SGN>(xr[14], xi[14], -C2, C2);      // w16^6
    tw16<SGN>(xr[7],  xi[7],  S1,  C1);      // w16^3
    tw16<SGN>(xr[11], xi[11], -C2, C2);      // w16^6
    tw16<SGN>(xr[15], xi[15], -C1, -S1);     // w16^9
    #pragma unroll
    for (int k4 = 0; k4 < 4; ++k4)
        dft4<SGN>(xr[4*k4+0], xi[4*k4+0], xr[4*k4+1], xi[4*k4+1],
                  xr[4*k4+2], xi[4*k4+2], xr[4*k4+3], xi[4*k4+3]);
}

// Log-depth 16-twiddle ladder: given w = (c,s), derive w^2, w^3, w^4 once;
// tw_k = w^{4g} * w^{k&3}. Serial dependency depth ~5 complex mults instead
// of the 15-step recurrence (which throttled ILP in the store loops).
#define TWLADDER_INIT(c_, s_)                                              \
    float w1r_ = (c_), w1i_ = (s_), w2r_, w2i_, w3r_, w3i_, w4r_, w4i_;    \
    cmulf(w2r_, w2i_, w1r_, w1i_, w1r_, w1i_);                             \
    cmulf(w3r_, w3i_, w2r_, w2i_, w1r_, w1i_);                             \
    cmulf(w4r_, w4i_, w2r_, w2i_, w2r_, w2i_);                             \
    float bgr_ = 1.f, bgi_ = 0.f;

#define TWLADDER_GET(k_, twr_, twi_)                                       \
    {                                                                      \
        const int j_ = (k_) & 3;                                           \
        if      (j_ == 0) { twr_ = bgr_; twi_ = bgi_; }                    \
        else if (j_ == 1) cmulf(twr_, twi_, bgr_, bgi_, w1r_, w1i_);       \
        else if (j_ == 2) cmulf(twr_, twi_, bgr_, bgi_, w2r_, w2i_);       \
        else              cmulf(twr_, twi_, bgr_, bgi_, w3r_, w3i_);       \
    }

#define TWLADDER_STEP(k_)                                                  \
    if (((k_) & 3) == 3 && (k_) < 15) {                                    \
        float nr_, ni_;                                                    \
        cmulf(nr_, ni_, bgr_, bgi_, w4r_, w4i_);                           \
        bgr_ = nr_; bgi_ = ni_;                                            \
    }

// ---------------- dispersion via overlap-save FFT ----------------
// N=4096=16^3 complex FFT, 256 threads, one 16-pt DFT per thread per stage.
// Forward: 3 DIF radix-16 stages -> digit-reversed order; multiply by the
// pre-digit-reversed G; inverse: 3 DIT stages back to natural order.
// Fwd stage 3 + G-mult + inv stage 3 are fused in registers (no LDS pass).
// LDS pad: +2 floats per 32 -> stage-1/2 strided patterns are 2-way (free).
#define FFTN  4096
#define FSTEP 3096                 // valid outputs per segment (4096-1001+1)
#define PH(i) ((i) + ((((unsigned)(i)) >> 5) << 1))
#define LDSN  4352                 // PH(4095)=4349, rounded up

__global__ __launch_bounds__(256, 2) void disp_fft(
    const float* __restrict__ XR, const float* __restrict__ XI,
    const float* __restrict__ Gb,
    float* __restrict__ AR, float* __restrict__ AI, int La)
{
    __shared__ __align__(16) float sre[LDSN];
    __shared__ __align__(16) float sim[LDSN];
    const int t = threadIdx.x;
    const int seq = blockIdx.y;           // b*2 + mode
    const int b = seq >> 1;
    const int tile0 = blockIdx.x * FSTEP;
    const int Lin = La + (DTAPS_C - 1);   // current input length
    const int rem_in = Lin - tile0;       // >= 1001
    const float* xr = XR + (size_t)seq * SSTR + tile0;
    const float* xi = XI + (size_t)seq * SSTR + tile0;

    // ---- load segment (zero-padded tail) ----
    #pragma unroll
    for (int q = 0; q < 4; ++q) {
        const int i0 = q * 1024 + t * 4;
        float4 vr4 = make_float4(0.f, 0.f, 0.f, 0.f);
        float4 vi4 = make_float4(0.f, 0.f, 0.f, 0.f);
        if (i0 + 3 < rem_in) {
            vr4 = *(const float4*)(xr + i0);
            vi4 = *(const float4*)(xi + i0);
        } else {
            if (i0 + 0 < rem_in) { vr4.x = xr[i0+0]; vi4.x = xi[i0+0]; }
            if (i0 + 1 < rem_in) { vr4.y = xr[i0+1]; vi4.y = xi[i0+1]; }
            if (i0 + 2 < rem_in) { vr4.z = xr[i0+2]; vi4.z = xi[i0+2]; }
        }
        const int p = PH(i0);             // i0%32 <= 28 -> 4 contiguous
        sre[p+0] = vr4.x; sre[p+1] = vr4.y; sre[p+2] = vr4.z; sre[p+3] = vr4.w;
        sim[p+0] = vi4.x; sim[p+1] = vi4.y; sim[p+2] = vi4.z; sim[p+3] = vi4.w;
    }
    __syncthreads();

    float vr[16], vi[16];

    // ---- FWD stage 1: L=4096, j=t, addr = t + 256*m -> PH = PH(t) + 272*m
    {
        const int base = PH(t);
        #pragma unroll
        for (int m = 0; m < 16; ++m) { vr[m] = sre[base + 272*m]; vi[m] = sim[base + 272*m]; }
        dft16<-1>(vr, vi);
        float s, c; sincosf((float)(-2.0 * PI_D / 4096.0) * (float)t, &s, &c);
        TWLADDER_INIT(c, s)
        #pragma unroll
        for (int k = 0; k < 16; ++k) {
            const int sl = 4*(k&3) + (k>>2);
            float twr, twi;
            TWLADDER_GET(k, twr, twi)
            sre[base + 272*k] = vr[sl]*twr - vi[sl]*twi;
            sim[base + 272*k] = vr[sl]*twi + vi[sl]*twr;
            TWLADDER_STEP(k)
        }
    }
    __syncthreads();

    // ---- FWD stage 2: L=256, blk=t>>4, j=t&15, addr = 256blk + j + 16m
    {
        const int j = t & 15, blk = t >> 4;
        const int base = 272*blk + j;
        #pragma unroll
        for (int m = 0; m < 16; ++m) {
            const int o = base + 16*m + 2*(m>>1);
            vr[m] = sre[o]; vi[m] = sim[o];
        }
        dft16<-1>(vr, vi);
        float s, c; sincosf((float)(-2.0 * PI_D / 256.0) * (float)j, &s, &c);
        TWLADDER_INIT(c, s)
        #pragma unroll
        for (int k = 0; k < 16; ++k) {
            const int sl = 4*(k&3) + (k>>2);
            const int o = base + 16*k + 2*(k>>1);
            float twr, twi;
            TWLADDER_GET(k, twr, twi)
            sre[o] = vr[sl]*twr - vi[sl]*twi;
            sim[o] = vr[sl]*twi + vi[sl]*twr;
            TWLADDER_STEP(k)
        }
    }
    __syncthreads();

    // ---- fused: FWD stage 3 (contig 16, no twiddle) + G multiply + INV stage 3
    {
        const int base = 16*t + 2*(t>>1);    // PH(16t + m) = base + m
        #pragma unroll
        for (int m = 0; m < 16; ++m) { vr[m] = sre[base + m]; vi[m] = sim[base + m]; }
        dft16<-1>(vr, vi);
        const float2* gp = ((const float2*)Gb) + ((size_t)b << 12) + (t << 4);
        float wr2[16], wi2[16];
        #pragma unroll
        for (int k = 0; k < 16; ++k) {
            const int sl = 4*(k&3) + (k>>2);
            const float2 g = gp[k];          // G at digit-reversed pos 16t+k
            wr2[k] = vr[sl]*g.x - vi[sl]*g.y;
            wi2[k] = vr[sl]*g.y + vi[sl]*g.x;
        }
        dft16<1>(wr2, wi2);
        #pragma unroll
        for (int m = 0; m < 16; ++m) {
            const int sl = 4*(m&3) + (m>>2);
            sre[base + m] = wr2[sl]; sim[base + m] = wi2[sl];
        }
    }
    __syncthreads();

    // ---- INV stage 2': conj twiddle on input, iDFT16, write to m-slots
    {
        const int j = t & 15, blk = t >> 4;
        const int base = 272*blk + j;
        float s, c; sincosf((float)(2.0 * PI_D / 256.0) * (float)j, &s, &c);
        TWLADDER_INIT(c, s)
        #pragma unroll
        for (int k = 0; k < 16; ++k) {
            const int o = base + 16*k + 2*(k>>1);
            const float a = sre[o], d = sim[o];
            float twr, twi;
            TWLADDER_GET(k, twr, twi)
            vr[k] = a*twr - d*twi; vi[k] = a*twi + d*twr;
            TWLADDER_STEP(k)
        }
        dft16<1>(vr, vi);
        #pragma unroll
        for (int m = 0; m < 16; ++m) {
            const int sl = 4*(m&3) + (m>>2);
            const int o = base + 16*m + 2*(m>>1);
            sre[o] = vr[sl]; sim[o] = vi[sl];
        }
    }
    __syncthreads();

    // ---- INV stage 1'
    {
        const int base = PH(t);
        float s, c; sincosf((float)(2.0 * PI_D / 4096.0) * (float)t, &s, &c);
        TWLADDER_INIT(c, s)
        #pragma unroll
        for (int k = 0; k < 16; ++k) {
            const float a = sre[base + 272*k], d = sim[base + 272*k];
            float twr, twi;
            TWLADDER_GET(k, twr, twi)
            vr[k] = a*twr - d*twi; vi[k] = a*twi + d*twr;
            TWLADDER_STEP(k)
        }
        dft16<1>(vr, vi);
        #pragma unroll
        for (int m = 0; m < 16; ++m) {
            const int sl = 4*(m&3) + (m>>2);
            sre[base + 272*m] = vr[sl]; sim[base + 272*m] = vi[sl];
        }
    }
    __syncthreads();

    // ---- store valid outputs [0, nout) ----
    const int nout = min(FSTEP, La - tile0);
    float* arp = AR + (size_t)seq * SSTR + tile0;
    float* aip = AI + (size_t)seq * SSTR + tile0;
    #pragma unroll
    for (int q = 0; q < 4; ++q) {
        const int i0 = q * 1024 + t * 4;
        if (i0 >= nout) continue;
        const int p = PH(i0);
        if (i0 + 3 < nout) {
            *(float4*)(arp + i0) = make_float4(sre[p], sre[p+1], sre[p+2], sre[p+3]);
            *(float4*)(aip + i0) = make_float4(sim[p], sim[p+1], sim[p+2], sim[p+3]);
        } else {
            for (int k = 0; k < 4; ++k) if (i0 + k < nout) {
                arp[i0+k] = sre[p+k]; aip[i0+k] = sim[p+k];
            }
        }
    }
}

// ---------------- nonlinear conv + rotation ----------------
// BARRIER-FREE per-wave staging (verified round-11/14 structure). NEW in r15:
// the 16 epilogue sincosf are replaced by native __sinf/__cosf (v_sin/v_cos
// + trivial reduction, ~4 ops vs ~20-40 for the precise OCML path). The
// rotation angles are small (|theta*coef| << pi), where the HW ops are
// accurate to a few ULP -> output perturbation ~1e-6, far below tolerance.
#define K2_BLOCK 256
#define K2_TILE  2048
#define WOUT     512               // outputs per wave
#define K2_WLDSL 632               // per-wave logical window (512 + 120)
#define K2_WLDSP 720               // SWZ(631)=707, rounded to 16B multiple

#define N_CH8(W_, V_, N_, P0, P1, KK)                                      \
  {                                                                        \
    LD4V(N_[0],N_[1],N_[2],N_[3], sp[P0]);                                 \
    LD4V(N_[4],N_[5],N_[6],N_[7], sp[P1]);                                 \
    _Pragma("unroll")                                                      \
    for (int d = 0; d < 8; ++d) {                                          \
      const float av = nkA[(KK) + d], bv = nkB[(KK) + d];                  \
      _Pragma("unroll")                                                    \
      for (int j = 0; j < 8; ++j) {                                        \
        const float xv = (j + d < 8) ? W_[j + d] : V_[j + d - 8];          \
        th0[j] = fmaf(av, xv, th0[j]);                                     \
        th1[j] = fmaf(bv, xv, th1[j]);                                     \
      }                                                                    \
    }                                                                      \
  }

__global__ __launch_bounds__(K2_BLOCK, 4) void nl_rotate(
    const float* __restrict__ AR, const float* __restrict__ AI,
    const float* __restrict__ NKg, const float* __restrict__ COEF,
    float* __restrict__ XR, float* __restrict__ XI,
    float* __restrict__ OUT, int Lb, int finalstep)
{
    __shared__ __align__(16) float sw[4][2][K2_WLDSP];   // 23 KB
    const int b = blockIdx.y;
    const int tile0 = blockIdx.x * K2_TILE;
    const int nout  = min(K2_TILE, Lb - tile0);
    const int cnt   = nout + NTAPS_C - 1;
    const int w    = threadIdx.x >> 6;       // wave id 0..3
    const int lane = threadIdx.x & 63;
    const int wbase = w * WOUT;              // wave window start within tile
    const float* ar0 = AR + (size_t)(2 * b + 0) * SSTR + tile0;
    const float* ai0 = AI + (size_t)(2 * b + 0) * SSTR + tile0;
    const float* ar1 = AR + (size_t)(2 * b + 1) * SSTR + tile0;
    const float* ai1 = AI + (size_t)(2 * b + 1) * SSTR + tile0;

    float* sp0 = sw[w][0];
    float* sp1 = sw[w][1];

    // ---- per-wave staging: float4 loads, power, float4 LDS writes ----
    #pragma unroll
    for (int q = 0; q < 3; ++q) {
        const int i0 = q * 256 + lane * 4;   // local window index
        if (i0 < K2_WLDSL) {
            const int gi = wbase + i0;       // global-in-tile index
            float4 p0v = make_float4(0.f, 0.f, 0.f, 0.f);
            float4 p1v = make_float4(0.f, 0.f, 0.f, 0.f);
            if (gi + 3 < cnt) {
                float4 a4 = *(const float4*)(ar0 + gi);
                float4 c4 = *(const float4*)(ai0 + gi);
                float4 d4 = *(const float4*)(ar1 + gi);
                float4 e4 = *(const float4*)(ai1 + gi);
                p0v.x = fmaf(a4.x, a4.x, c4.x * c4.x);
                p0v.y = fmaf(a4.y, a4.y, c4.y * c4.y);
                p0v.z = fmaf(a4.z, a4.z, c4.z * c4.z);
                p0v.w = fmaf(a4.w, a4.w, c4.w * c4.w);
                p1v.x = fmaf(d4.x, d4.x, e4.x * e4.x);
                p1v.y = fmaf(d4.y, d4.y, e4.y * e4.y);
                p1v.z = fmaf(d4.z, d4.z, e4.z * e4.z);
                p1v.w = fmaf(d4.w, d4.w, e4.w * e4.w);
            } else {
                float p0a[4] = {0.f, 0.f, 0.f, 0.f};
                float p1a[4] = {0.f, 0.f, 0.f, 0.f};
                #pragma unroll
                for (int u = 0; u < 4; ++u) {
                    const int i = gi + u;
                    if (i < cnt) {
                        float a = ar0[i], c = ai0[i];
                        float d = ar1[i], e = ai1[i];
                        p0a[u] = fmaf(a, a, c * c);
                        p1a[u] = fmaf(d, d, e * e);
                    }
                }
                p0v = make_float4(p0a[0], p0a[1], p0a[2], p0a[3]);
                p1v = make_float4(p1a[0], p1a[1], p1a[2], p1a[3]);
            }
            const int p = SWZ(i0);   // i0%32 <= 28 -> 4 contiguous, 16B-aligned
            *(float4*)&sp0[p] = p0v;
            *(float4*)&sp1[p] = p1v;
        }
    }

    // ---- hoisted rotation operand loads (issue-early; drain under conv) ----
    const int t0 = wbase + lane * 8;         // global-in-tile output base
    const int lt0 = lane * 8;                // local-in-window output base
    float ra0[8], rb0[8], ra1[8], rb1[8];
    {
        const float* art0 = ar0 + t0 + NTAPS_C / 2;   // = AR[...][tg+50]
        const float* ait0 = ai0 + t0 + NTAPS_C / 2;
        const float* art1 = ar1 + t0 + NTAPS_C / 2;
        const float* ait1 = ai1 + t0 + NTAPS_C / 2;
        #pragma unroll
        for (int j = 0; j < 8; ++j) {
            ra0[j] = art0[j]; rb0[j] = ait0[j];
            ra1[j] = art1[j]; rb1[j] = ait1[j];
        }
    }

    // fence LDS writes -> reads within the wave (no block barrier needed)
    asm volatile("s_waitcnt lgkmcnt(0)" ::: "memory");
    __builtin_amdgcn_sched_barrier(0);

    if (t0 >= nout) return;

    float th0[8], th1[8];
    #pragma unroll
    for (int j = 0; j < 8; ++j) { th0[j] = 0.f; th1[j] = 0.f; }
    const float* nkb = NKg + b * 4 * NKP;

    const int a0 = SWZ(lt0 + 16), a1 = SWZ(lt0 + 20), a2 = SWZ(lt0 + 24), a3 = SWZ(lt0 + 28);
    const int a4 = SWZ(lt0 + 32), a5 = SWZ(lt0 + 36), a6 = SWZ(lt0 + 40), a7 = SWZ(lt0 + 44);

    for (int im = 0; im < 2; ++im) {
        const float* sp  = im ? sp1 : sp0;
        const float* nkA = nkb + (0 * 2 + im) * NKP;   // output mode 0
        const float* nkB = nkb + (1 * 2 + im) * NKP;   // output mode 1
        float U[8], V[8], N[8];
        LD4V(U[0],U[1],U[2],U[3], sp[SWZ(lt0)]);
        LD4V(U[4],U[5],U[6],U[7], sp[SWZ(lt0 + 4)]);
        LD4V(V[0],V[1],V[2],V[3], sp[SWZ(lt0 + 8)]);
        LD4V(V[4],V[5],V[6],V[7], sp[SWZ(lt0 + 12)]);
        // 104 padded taps = 13 chunks (coeffs 101..103 are zero)
        N_CH8(U, V, N, a0,       a1,        0);
        N_CH8(V, N, U, a2,       a3,        8);
        N_CH8(N, U, V, a4,       a5,       16);
        N_CH8(U, V, N, a6,       a7,       24);
        N_CH8(V, N, U, a0 + 36,  a1 + 36,  32);
        N_CH8(N, U, V, a2 + 36,  a3 + 36,  40);
        N_CH8(U, V, N, a4 + 36,  a5 + 36,  48);
        N_CH8(V, N, U, a6 + 36,  a7 + 36,  56);
        N_CH8(N, U, V, a0 + 72,  a1 + 72,  64);
        N_CH8(U, V, N, a2 + 72,  a3 + 72,  72);
        N_CH8(V, N, U, a4 + 72,  a5 + 72,  80);
        N_CH8(N, U, V, a6 + 72,  a7 + 72,  88);
        N_CH8(U, V, N, a0 + 108, a1 + 108, 96);
    }

    const float coef = COEF[b];
    const int tg = tile0 + t0;

    float or0[8], oi0[8], or1[8], oi1[8];
    #pragma unroll
    for (int j = 0; j < 8; ++j) {
        const float x0 = th0[j] * coef;
        const float x1 = th1[j] * coef;
        const float s0 = __sinf(x0), c0 = __cosf(x0);
        const float s1 = __sinf(x1), c1 = __cosf(x1);
        float a0v = ra0[j], b0v = rb0[j];
        float a1v = ra1[j], b1v = rb1[j];
        or0[j] = fmaf(a0v, c0, -b0v * s0);
        oi0[j] = fmaf(a0v, s0,  b0v * c0);
        or1[j] = fmaf(a1v, c1, -b1v * s1);
        oi1[j] = fmaf(a1v, s1,  b1v * c1);
    }

    const int rem = nout - t0;
    if (finalstep) {
        // out[b][t][c][ri] contiguous float4 per t
        float4* op = (float4*)(OUT + (size_t)(b * Lb + tg) * 4);
        if (rem >= 8) {
            #pragma unroll
            for (int j = 0; j < 8; ++j) op[j] = make_float4(or0[j], oi0[j], or1[j], oi1[j]);
        } else {
            for (int j = 0; j < rem; ++j) op[j] = make_float4(or0[j], oi0[j], or1[j], oi1[j]);
        }
    } else {
        float* xr0 = XR + (size_t)(2 * b + 0) * SSTR + tg;
        float* xi0 = XI + (size_t)(2 * b + 0) * SSTR + tg;
        float* xr1 = XR + (size_t)(2 * b + 1) * SSTR + tg;
        float* xi1 = XI + (size_t)(2 * b + 1) * SSTR + tg;
        if (rem >= 8) {
            ((float4*)xr0)[0] = make_float4(or0[0], or0[1], or0[2], or0[3]);
            ((float4*)xr0)[1] = make_float4(or0[4], or0[5], or0[6], or0[7]);
            ((float4*)xi0)[0] = make_float4(oi0[0], oi0[1], oi0[2], oi0[3]);
            ((float4*)xi0)[1] = make_float4(oi0[4], oi0[5], oi0[6], oi0[7]);
            ((float4*)xr1)[0] = make_float4(or1[0], or1[1], or1[2], or1[3]);
            ((float4*)xr1)[1] = make_float4(or1[4], or1[5], or1[6], or1[7]);
            ((float4*)xi1)[0] = make_float4(oi1[0], oi1[1], oi1[2], oi1[3]);
            ((float4*)xi1)[1] = make_float4(oi1[4], oi1[5], oi1[6], oi1[7]);
        } else {
            for (int j = 0; j < rem; ++j) {
                xr0[j] = or0[j]; xi0[j] = oi0[j];
                xr1[j] = or1[j]; xi1[j] = oi1[j];
            }
        }
    }
}

// ---------------- launch ----------------
extern "C" void kernel_launch(void* const* d_in, const int* in_sizes, int n_in,
                              void* d_out, int out_size, void* d_ws, size_t ws_size,
                              hipStream_t stream)
{
    const float* x_real = (const float*)d_in[0];
    const float* x_imag = (const float*)d_in[1];
    const float* task   = (const float*)d_in[2];
    const float* W1     = (const float*)d_in[3];
    const float* b1     = (const float*)d_in[4];
    const float* W2     = (const float*)d_in[5];
    const float* b2     = (const float*)d_in[6];
    float* out = (float*)d_out;
    float* ws  = (float*)d_ws;

    float* HR   = ws;
    float* HI   = HR + B_C * DTAPS_C;
    float* NKg  = HI + B_C * DTAPS_C;
    float* COEF = NKg + B_C * 4 * NKP;
    float* Gb   = ws + 16384;                       // B*4096 complex = 32768 f
    float* XR = ws + 16384 + 32768;
    float* XI = XR + (size_t)B_C * 2 * SEQ_C;
    float* AR = XI + (size_t)B_C * 2 * SEQ_C;
    float* AI = AR + (size_t)B_C * 2 * SEQ_C;

    build_disp<<<dim3(32, B_C), 256, 0, stream>>>(task, HR, HI);
    build_nk<<<1, 512, 0, stream>>>(task, W1, b1, W2, b2, NKg, COEF);
    build_G<<<dim3(128, B_C), 256, 0, stream>>>(HR, HI, Gb);
    {
        int n = B_C * SEQ_C;
        transpose_in<<<(n + 255) / 256, 256, 0, stream>>>(x_real, x_imag, XR, XI);
    }

    int L = SEQ_C;
    for (int s = 0; s < STEPS_C; ++s) {
        const int La = L - (DTAPS_C - 1);     // after dispersion FIR
        const int Lb = La - (NTAPS_C - 1);    // after nonlinear conv + trim
        dim3 g1((La + FSTEP - 1) / FSTEP, B_C * NM);
        disp_fft<<<g1, 256, 0, stream>>>(XR, XI, Gb, AR, AI, La);
        dim3 g2((Lb + K2_TILE - 1) / K2_TILE, B_C);
        nl_rotate<<<g2, K2_BLOCK, 0, stream>>>(AR, AI, NKg, COEF, XR, XI, out,
                                               Lb, (s == STEPS_C - 1) ? 1 : 0);
        L = Lb;
    }
}

// Round 16
// 303.519 us; speedup vs baseline: 1.1349x; 1.0165x over previous
//
#include <hip/hip_runtime.h>

// ---------------- problem constants ----------------
#define NM      2          // NMODES
#define STEPS_C 5
#define DTAPS_C 1001
#define NTAPS_C 101
#define HID_C   100
#define B_C     4
#define SEQ_C   500000
#define SSTR    SEQ_C      // per-(b,mode) stride in planar work buffers
#define NKP     104        // nonlinear taps padded to multiple of 8 (zeros)
#define FS_NOM_D 160000000000.0
#define PI_D 3.14159265358979323846

// LDS bank swizzle for nl_rotate: insert 4 pad floats every 32
#define SWZ(L) ((L) + ((((unsigned)(L)) >> 5) << 2))

#define LD4V(A0,A1,A2,A3, SRC) { float4 q_ = *(const float4*)&(SRC); \
    A0=q_.x; A1=q_.y; A2=q_.z; A3=q_.w; }

// complex multiply helper (outputs must not alias inputs)
__device__ __forceinline__ void cmulf(float& o_r, float& o_i,
                                      float a_r, float a_i, float b_r, float b_i)
{ o_r = a_r * b_r - a_i * b_i; o_i = a_r * b_i + a_i * b_r; }

// ---------------- dispersion kernel build (parallel DFT) ----------------
// grid (32, B), 256 thr. Block stages the 1001 freq-domain samples (fp64) in
// LDS; 32 outputs/block, 8-way k-split per output, shfl_xor reduce.
__global__ void build_disp(const float* __restrict__ task,
                           float* __restrict__ HR, float* __restrict__ HI)
{
    __shared__ double skr[DTAPS_C], ski[DTAPS_C];
    const int b = blockIdx.y;
    const double Fs = (double)task[b * 4 + 2];
    const double c_kms = 299792458.0 / 1000.0;
    const double Fc    = 299792458.0 / 1.55e-6;
    const double lamb  = c_kms / Fc;
    const double beta2 = -(16.5 * lamb * lamb) / (2.0 * PI_D * c_kms) / 1000.0;
    const double dz    = -400000.0;   // -(L_FIBER/STEP)

    for (int k = threadIdx.x; k < DTAPS_C; k += blockDim.x) {
        double fk = ((k <= DTAPS_C / 2) ? (double)k : (double)(k - DTAPS_C)) / (double)DTAPS_C;
        double om = 2.0 * PI_D * Fs * fk;
        double ph = 0.5 * beta2 * om * om * dz;
        ph = fmod(ph, 2.0 * PI_D);
        double s, c; sincos(ph, &s, &c);
        skr[k] = c;  ski[k] = -s;     // exp(-i*phase)
    }
    __syncthreads();

    const int ln = threadIdx.x >> 3;           // 0..31 output slot
    const int kp = threadIdx.x & 7;            // 0..7  k-part
    const int n  = blockIdx.x * 32 + ln;       // 0..1023
    double dr = 0.0, di = 0.0;
    {
        const int nn = (n < DTAPS_C) ? n : 0;
        // twiddle e^{+2pi i k n/1001}: start at k=kp, step 8
        const int r0 = (nn * kp) % DTAPS_C;
        const int rs = (nn * 8) % DTAPS_C;
        double a0 = 2.0 * PI_D * (double)r0 / (double)DTAPS_C;
        double as = 2.0 * PI_D * (double)rs / (double)DTAPS_C;
        double s0, c0, ss, cs;
        sincos(a0, &s0, &c0);
        sincos(as, &ss, &cs);
        for (int k = kp; k < DTAPS_C; k += 8) {
            dr += skr[k] * c0 - ski[k] * s0;
            di += skr[k] * s0 + ski[k] * c0;
            const double nc = c0 * cs - s0 * ss;
            s0 = c0 * ss + s0 * cs;
            c0 = nc;
        }
    }
    // reduce over kp (lanes differing in low 3 bits share one n)
    #pragma unroll
    for (int m = 1; m <= 4; m <<= 1) {
        dr += __shfl_xor(dr, m, 64);
        di += __shfl_xor(di, m, 64);
    }
    if (kp == 0 && n < DTAPS_C) {
        int m = n + DTAPS_C / 2; if (m >= DTAPS_C) m -= DTAPS_C;  // fftshift
        HR[b * DTAPS_C + m] = (float)(dr / (double)DTAPS_C);
        HI[b * DTAPS_C + m] = (float)(di / (double)DTAPS_C);
    }
}

// ---------------- filter spectrum for overlap-save FFT conv ----------------
// G[f] = (1/4096) * sum_k h[k] * e^{+2pi i f k / 4096}, stored at the
// digit-reversed (base-16, 3 digits) position so the FFT needs no reorder.
// grid (128, B), 256 thr: 32 outputs/block, 8-way k-split, shfl_xor reduce.
__global__ void build_G(const float* __restrict__ HR, const float* __restrict__ HI,
                        float* __restrict__ Gb)
{
    __shared__ float shr[DTAPS_C], shi[DTAPS_C];
    const int b = blockIdx.y;
    for (int k = threadIdx.x; k < DTAPS_C; k += blockDim.x) {
        shr[k] = HR[b * DTAPS_C + k];
        shi[k] = HI[b * DTAPS_C + k];
    }
    __syncthreads();

    const int ln = threadIdx.x >> 3;
    const int kp = threadIdx.x & 7;
    const int f  = blockIdx.x * 32 + ln;       // 0..4095
    double ar = 0.0, ai = 0.0;
    {
        // twiddle e^{+2pi i f k/4096}: start k=kp, step 8
        const int r0 = (f * kp) & 4095;
        const int rs = (f * 8) & 4095;
        double a0 = (2.0 * PI_D / 4096.0) * (double)r0;
        double as = (2.0 * PI_D / 4096.0) * (double)rs;
        double s0, c0, ss, cs;
        sincos(a0, &s0, &c0);
        sincos(as, &ss, &cs);
        for (int k = kp; k < DTAPS_C; k += 8) {
            const double hre = (double)shr[k], him = (double)shi[k];
            ar += hre * c0 - him * s0;
            ai += hre * s0 + him * c0;
            const double nc = c0 * cs - s0 * ss;
            s0 = c0 * ss + s0 * cs;
            c0 = nc;
        }
    }
    #pragma unroll
    for (int m = 1; m <= 4; m <<= 1) {
        ar += __shfl_xor(ar, m, 64);
        ai += __shfl_xor(ai, m, 64);
    }
    if (kp == 0) {
        const int p = ((f & 15) << 8) + (((f >> 4) & 15) << 4) + (f >> 8);
        Gb[(size_t)(b * 4096 + p) * 2 + 0] = (float)(ar * (1.0 / 4096.0));
        Gb[(size_t)(b * 4096 + p) * 2 + 1] = (float)(ai * (1.0 / 4096.0));
    }
}

// ---------------- nonlinear kernel build (tiny MLP) ----------------
__global__ void build_nk(const float* __restrict__ task,
                         const float* __restrict__ W1, const float* __restrict__ b1,
                         const float* __restrict__ W2, const float* __restrict__ b2,
                         float* __restrict__ NKg, float* __restrict__ COEF)
{
    const int tid = threadIdx.x;
    for (int i = tid; i < B_C * 4 * NKP; i += blockDim.x) NKg[i] = 0.f;
    if (tid < B_C) {
        float pdbm = task[tid * 4 + 0];
        float P = 0.001f * powf(10.f, pdbm * 0.1f) / (float)NM;
        COEF[tid] = (float)(0.0016567 * 400000.0) * P;  // GAMMA*DZ*P
    }
    __syncthreads();
    if (tid < B_C * NTAPS_C) {
        const int b = tid / NTAPS_C, tap = tid % NTAPS_C;
        float Fsn = task[b * 4 + 2] * (float)(1.0 / FS_NOM_D);
        float Ts = 1.f / Fsn, Ts2 = Ts * Ts;
        float pos = fabsf((float)(tap - NTAPS_C / 2)) * (1.f / 200.f);
        float inp = pos * Ts2;
        float o0 = b2[0], o1 = b2[1], o2 = b2[2], o3 = b2[3];
        for (int j = 0; j < HID_C; ++j) {
            float h = fmaxf(fmaf(inp, W1[j], b1[j]), 0.f);
            o0 = fmaf(h, W2[j * 4 + 0], o0);
            o1 = fmaf(h, W2[j * 4 + 1], o1);
            o2 = fmaf(h, W2[j * 4 + 2], o2);
            o3 = fmaf(h, W2[j * 4 + 3], o3);
        }
        float sc = Ts2 * expf(-pos * Ts2);
        NKg[(b * 4 + 0) * NKP + tap] = o0 * sc;
        NKg[(b * 4 + 1) * NKP + tap] = o1 * sc;
        NKg[(b * 4 + 2) * NKP + tap] = o2 * sc;
        NKg[(b * 4 + 3) * NKP + tap] = o3 * sc;
    }
}

// ---------------- input transpose (B,SEQ,2) -> planar (B,2,SEQ) -------------
__global__ void transpose_in(const float* __restrict__ xr_in, const float* __restrict__ xi_in,
                             float* __restrict__ XR, float* __restrict__ XI)
{
    int idx = blockIdx.x * blockDim.x + threadIdx.x;   // over B*SEQ
    if (idx >= B_C * SEQ_C) return;
    int b = idx / SEQ_C, t = idx - b * SEQ_C;
    float2 vr = ((const float2*)xr_in)[idx];
    float2 vi = ((const float2*)xi_in)[idx];
    XR[(size_t)(b * 2 + 0) * SSTR + t] = vr.x;
    XR[(size_t)(b * 2 + 1) * SSTR + t] = vr.y;
    XI[(size_t)(b * 2 + 0) * SSTR + t] = vi.x;
    XI[(size_t)(b * 2 + 1) * SSTR + t] = vi.y;
}

// ---------------- radix-16 building blocks (all-register, static idx) -------
template<int SGN>
__device__ __forceinline__ void dft4(float& ar, float& ai, float& br, float& bi,
                                     float& cr, float& ci, float& dr, float& di)
{
    float t0r = ar + cr, t0i = ai + ci;
    float t1r = ar - cr, t1i = ai - ci;
    float t2r = br + dr, t2i = bi + di;
    float t3r = br - dr, t3i = bi - di;
    ar = t0r + t2r; ai = t0i + t2i;          // y0
    cr = t0r - t2r; ci = t0i - t2i;          // y2
    if (SGN < 0) {                           // fwd: y1 = t1 - i t3, y3 = t1 + i t3
        br = t1r + t3i; bi = t1i - t3r;
        dr = t1r - t3i; di = t1i + t3r;
    } else {                                 // inv: conj
        br = t1r - t3i; bi = t1i + t3r;
        dr = t1r + t3i; di = t1i - t3r;
    }
}

template<int SGN>
__device__ __forceinline__ void tw16(float& r, float& i, float c, float s)
{
    // multiply by (c + SGN * i * s)
    float nr, ni;
    if (SGN < 0) { nr = r * c + i * s; ni = i * c - r * s; }
    else         { nr = r * c - i * s; ni = i * c + r * s; }
    r = nr; i = ni;
}

// In-place DFT16. Input x[m] at slot m; output X[k1+4k2] lands at slot 4*k1+k2
// i.e. X[k] at slot SIG(k) = 4*(k&3)+(k>>2) (an involution).
template<int SGN>
__device__ __forceinline__ void dft16(float (&xr)[16], float (&xi)[16])
{
    #pragma unroll
    for (int n1 = 0; n1 < 4; ++n1)
        dft4<SGN>(xr[n1], xi[n1], xr[n1+4], xi[n1+4],
                  xr[n1+8], xi[n1+8], xr[n1+12], xi[n1+12]);
    const float C1 = 0.923879532511286756f, S1 = 0.382683432365089772f;
    const float C2 = 0.707106781186547524f;
    tw16<SGN>(xr[5],  xi[5],  C1,  S1);      // w16^1
    tw16<SGN>(xr[9],  xi[9],  C2,  C2);      // w16^2
    tw16<SGN>(xr[13], xi[13], S1,  C1);      // w16^3
    tw16<SGN>(xr[6],  xi[6],  C2,  C2);      // w16^2
    tw16<SGN>(xr[10], xi[10], 0.f, 1.f);     // w16^4
    tw16<SGN>(xr[14], xi[14], -C2, C2);      // w16^6
    tw16<SGN>(xr[7],  xi[7],  S1,  C1);      // w16^3
    tw16<SGN>(xr[11], xi[11], -C2, C2);      // w16^6
    tw16<SGN>(xr[15], xi[15], -C1, -S1);     // w16^9
    #pragma unroll
    for (int k4 = 0; k4 < 4; ++k4)
        dft4<SGN>(xr[4*k4+0], xi[4*k4+0], xr[4*k4+1], xi[4*k4+1],
                  xr[4*k4+2], xi[4*k4+2], xr[4*k4+3], xi[4*k4+3]);
}

// Log-depth 16-twiddle ladder: given w = (c,s), derive w^2, w^3, w^4 once;
// tw_k = w^{4g} * w^{k&3}. Serial dependency depth ~5 complex mults instead
// of the 15-step recurrence (which throttled ILP in the store loops).
#define TWLADDER_INIT(c_, s_)                                              \
    float w1r_ = (c_), w1i_ = (s_), w2r_, w2i_, w3r_, w3i_, w4r_, w4i_;    \
    cmulf(w2r_, w2i_, w1r_, w1i_, w1r_, w1i_);                             \
    cmulf(w3r_, w3i_, w2r_, w2i_, w1r_, w1i_);                             \
    cmulf(w4r_, w4i_, w2r_, w2i_, w2r_, w2i_);                             \
    float bgr_ = 1.f, bgi_ = 0.f;

#define TWLADDER_GET(k_, twr_, twi_)                                       \
    {                                                                      \
        const int j_ = (k_) & 3;                                           \
        if      (j_ == 0) { twr_ = bgr_; twi_ = bgi_; }                    \
        else if (j_ == 1) cmulf(twr_, twi_, bgr_, bgi_, w1r_, w1i_);       \
        else if (j_ == 2) cmulf(twr_, twi_, bgr_, bgi_, w2r_, w2i_);       \
        else              cmulf(twr_, twi_, bgr_, bgi_, w3r_, w3i_);       \
    }

#define TWLADDER_STEP(k_)                                                  \
    if (((k_) & 3) == 3 && (k_) < 15) {                                    \
        float nr_, ni_;                                                    \
        cmulf(nr_, ni_, bgr_, bgi_, w4r_, w4i_);                           \
        bgr_ = nr_; bgi_ = ni_;                                            \
    }

// ---------------- dispersion via overlap-save FFT ----------------
// N=4096=16^3 complex FFT, 256 threads, one 16-pt DFT per thread per stage.
// Forward: 3 DIF radix-16 stages -> digit-reversed order; multiply by the
// pre-digit-reversed G; inverse: 3 DIT stages back to natural order.
// Fwd stage 3 + G-mult + inv stage 3 are fused in registers (no LDS pass).
// LDS pad: +2 floats per 32 -> stage-1/2 strided patterns are 2-way (free).
// r16: twiddle-base sincosf -> native __sinf/__cosf (|x| <= 0.39 rad; ladder
// amplifies base error to ~2e-6, far below tolerance) — same lever that won
// in nl_rotate's epilogue (r15: -15 us).
#define FFTN  4096
#define FSTEP 3096                 // valid outputs per segment (4096-1001+1)
#define PH(i) ((i) + ((((unsigned)(i)) >> 5) << 1))
#define LDSN  4352                 // PH(4095)=4349, rounded up

__global__ __launch_bounds__(256, 2) void disp_fft(
    const float* __restrict__ XR, const float* __restrict__ XI,
    const float* __restrict__ Gb,
    float* __restrict__ AR, float* __restrict__ AI, int La)
{
    __shared__ __align__(16) float sre[LDSN];
    __shared__ __align__(16) float sim[LDSN];
    const int t = threadIdx.x;
    const int seq = blockIdx.y;           // b*2 + mode
    const int b = seq >> 1;
    const int tile0 = blockIdx.x * FSTEP;
    const int Lin = La + (DTAPS_C - 1);   // current input length
    const int rem_in = Lin - tile0;       // >= 1001
    const float* xr = XR + (size_t)seq * SSTR + tile0;
    const float* xi = XI + (size_t)seq * SSTR + tile0;

    // ---- load segment (zero-padded tail) ----
    #pragma unroll
    for (int q = 0; q < 4; ++q) {
        const int i0 = q * 1024 + t * 4;
        float4 vr4 = make_float4(0.f, 0.f, 0.f, 0.f);
        float4 vi4 = make_float4(0.f, 0.f, 0.f, 0.f);
        if (i0 + 3 < rem_in) {
            vr4 = *(const float4*)(xr + i0);
            vi4 = *(const float4*)(xi + i0);
        } else {
            if (i0 + 0 < rem_in) { vr4.x = xr[i0+0]; vi4.x = xi[i0+0]; }
            if (i0 + 1 < rem_in) { vr4.y = xr[i0+1]; vi4.y = xi[i0+1]; }
            if (i0 + 2 < rem_in) { vr4.z = xr[i0+2]; vi4.z = xi[i0+2]; }
        }
        const int p = PH(i0);             // i0%32 <= 28 -> 4 contiguous
        sre[p+0] = vr4.x; sre[p+1] = vr4.y; sre[p+2] = vr4.z; sre[p+3] = vr4.w;
        sim[p+0] = vi4.x; sim[p+1] = vi4.y; sim[p+2] = vi4.z; sim[p+3] = vi4.w;
    }
    __syncthreads();

    float vr[16], vi[16];

    // ---- FWD stage 1: L=4096, j=t, addr = t + 256*m -> PH = PH(t) + 272*m
    {
        const int base = PH(t);
        #pragma unroll
        for (int m = 0; m < 16; ++m) { vr[m] = sre[base + 272*m]; vi[m] = sim[base + 272*m]; }
        dft16<-1>(vr, vi);
        const float x = (float)(-2.0 * PI_D / 4096.0) * (float)t;
        const float s = __sinf(x), c = __cosf(x);
        TWLADDER_INIT(c, s)
        #pragma unroll
        for (int k = 0; k < 16; ++k) {
            const int sl = 4*(k&3) + (k>>2);
            float twr, twi;
            TWLADDER_GET(k, twr, twi)
            sre[base + 272*k] = vr[sl]*twr - vi[sl]*twi;
            sim[base + 272*k] = vr[sl]*twi + vi[sl]*twr;
            TWLADDER_STEP(k)
        }
    }
    __syncthreads();

    // ---- FWD stage 2: L=256, blk=t>>4, j=t&15, addr = 256blk + j + 16m
    {
        const int j = t & 15, blk = t >> 4;
        const int base = 272*blk + j;
        #pragma unroll
        for (int m = 0; m < 16; ++m) {
            const int o = base + 16*m + 2*(m>>1);
            vr[m] = sre[o]; vi[m] = sim[o];
        }
        dft16<-1>(vr, vi);
        const float x = (float)(-2.0 * PI_D / 256.0) * (float)j;
        const float s = __sinf(x), c = __cosf(x);
        TWLADDER_INIT(c, s)
        #pragma unroll
        for (int k = 0; k < 16; ++k) {
            const int sl = 4*(k&3) + (k>>2);
            const int o = base + 16*k + 2*(k>>1);
            float twr, twi;
            TWLADDER_GET(k, twr, twi)
            sre[o] = vr[sl]*twr - vi[sl]*twi;
            sim[o] = vr[sl]*twi + vi[sl]*twr;
            TWLADDER_STEP(k)
        }
    }
    __syncthreads();

    // ---- fused: FWD stage 3 (contig 16, no twiddle) + G multiply + INV stage 3
    {
        const int base = 16*t + 2*(t>>1);    // PH(16t + m) = base + m
        #pragma unroll
        for (int m = 0; m < 16; ++m) { vr[m] = sre[base + m]; vi[m] = sim[base + m]; }
        dft16<-1>(vr, vi);
        const float2* gp = ((const float2*)Gb) + ((size_t)b << 12) + (t << 4);
        float wr2[16], wi2[16];
        #pragma unroll
        for (int k = 0; k < 16; ++k) {
            const int sl = 4*(k&3) + (k>>2);
            const float2 g = gp[k];          // G at digit-reversed pos 16t+k
            wr2[k] = vr[sl]*g.x - vi[sl]*g.y;
            wi2[k] = vr[sl]*g.y + vi[sl]*g.x;
        }
        dft16<1>(wr2, wi2);
        #pragma unroll
        for (int m = 0; m < 16; ++m) {
            const int sl = 4*(m&3) + (m>>2);
            sre[base + m] = wr2[sl]; sim[base + m] = wi2[sl];
        }
    }
    __syncthreads();

    // ---- INV stage 2': conj twiddle on input, iDFT16, write to m-slots
    {
        const int j = t & 15, blk = t >> 4;
        const int base = 272*blk + j;
        const float x = (float)(2.0 * PI_D / 256.0) * (float)j;
        const float s = __sinf(x), c = __cosf(x);
        TWLADDER_INIT(c, s)
        #pragma unroll
        for (int k = 0; k < 16; ++k) {
            const int o = base + 16*k + 2*(k>>1);
            const float a = sre[o], d = sim[o];
            float twr, twi;
            TWLADDER_GET(k, twr, twi)
            vr[k] = a*twr - d*twi; vi[k] = a*twi + d*twr;
            TWLADDER_STEP(k)
        }
        dft16<1>(vr, vi);
        #pragma unroll
        for (int m = 0; m < 16; ++m) {
            const int sl = 4*(m&3) + (m>>2);
            const int o = base + 16*m + 2*(m>>1);
            sre[o] = vr[sl]; sim[o] = vi[sl];
        }
    }
    __syncthreads();

    // ---- INV stage 1'
    {
        const int base = PH(t);
        const float x = (float)(2.0 * PI_D / 4096.0) * (float)t;
        const float s = __sinf(x), c = __cosf(x);
        TWLADDER_INIT(c, s)
        #pragma unroll
        for (int k = 0; k < 16; ++k) {
            const float a = sre[base + 272*k], d = sim[base + 272*k];
            float twr, twi;
            TWLADDER_GET(k, twr, twi)
            vr[k] = a*twr - d*twi; vi[k] = a*twi + d*twr;
            TWLADDER_STEP(k)
        }
        dft16<1>(vr, vi);
        #pragma unroll
        for (int m = 0; m < 16; ++m) {
            const int sl = 4*(m&3) + (m>>2);
            sre[base + 272*m] = vr[sl]; sim[base + 272*m] = vi[sl];
        }
    }
    __syncthreads();

    // ---- store valid outputs [0, nout) ----
    const int nout = min(FSTEP, La - tile0);
    float* arp = AR + (size_t)seq * SSTR + tile0;
    float* aip = AI + (size_t)seq * SSTR + tile0;
    #pragma unroll
    for (int q = 0; q < 4; ++q) {
        const int i0 = q * 1024 + t * 4;
        if (i0 >= nout) continue;
        const int p = PH(i0);
        if (i0 + 3 < nout) {
            *(float4*)(arp + i0) = make_float4(sre[p], sre[p+1], sre[p+2], sre[p+3]);
            *(float4*)(aip + i0) = make_float4(sim[p], sim[p+1], sim[p+2], sim[p+3]);
        } else {
            for (int k = 0; k < 4; ++k) if (i0 + k < nout) {
                arp[i0+k] = sre[p+k]; aip[i0+k] = sim[p+k];
            }
        }
    }
}

// ---------------- nonlinear conv + rotation ----------------
// BARRIER-FREE per-wave staging (verified round-11/14 structure) + native
// __sinf/__cosf epilogue (r15, verified -15 us).
#define K2_BLOCK 256
#define K2_TILE  2048
#define WOUT     512               // outputs per wave
#define K2_WLDSL 632               // per-wave logical window (512 + 120)
#define K2_WLDSP 720               // SWZ(631)=707, rounded to 16B multiple

#define N_CH8(W_, V_, N_, P0, P1, KK)                                      \
  {                                                                        \
    LD4V(N_[0],N_[1],N_[2],N_[3], sp[P0]);                                 \
    LD4V(N_[4],N_[5],N_[6],N_[7], sp[P1]);                                 \
    _Pragma("unroll")                                                      \
    for (int d = 0; d < 8; ++d) {                                          \
      const float av = nkA[(KK) + d], bv = nkB[(KK) + d];                  \
      _Pragma("unroll")                                                    \
      for (int j = 0; j < 8; ++j) {                                        \
        const float xv = (j + d < 8) ? W_[j + d] : V_[j + d - 8];          \
        th0[j] = fmaf(av, xv, th0[j]);                                     \
        th1[j] = fmaf(bv, xv, th1[j]);                                     \
      }                                                                    \
    }                                                                      \
  }

__global__ __launch_bounds__(K2_BLOCK, 4) void nl_rotate(
    const float* __restrict__ AR, const float* __restrict__ AI,
    const float* __restrict__ NKg, const float* __restrict__ COEF,
    float* __restrict__ XR, float* __restrict__ XI,
    float* __restrict__ OUT, int Lb, int finalstep)
{
    __shared__ __align__(16) float sw[4][2][K2_WLDSP];   // 23 KB
    const int b = blockIdx.y;
    const int tile0 = blockIdx.x * K2_TILE;
    const int nout  = min(K2_TILE, Lb - tile0);
    const int cnt   = nout + NTAPS_C - 1;
    const int w    = threadIdx.x >> 6;       // wave id 0..3
    const int lane = threadIdx.x & 63;
    const int wbase = w * WOUT;              // wave window start within tile
    const float* ar0 = AR + (size_t)(2 * b + 0) * SSTR + tile0;
    const float* ai0 = AI + (size_t)(2 * b + 0) * SSTR + tile0;
    const float* ar1 = AR + (size_t)(2 * b + 1) * SSTR + tile0;
    const float* ai1 = AI + (size_t)(2 * b + 1) * SSTR + tile0;

    float* sp0 = sw[w][0];
    float* sp1 = sw[w][1];

    // ---- per-wave staging: float4 loads, power, float4 LDS writes ----
    #pragma unroll
    for (int q = 0; q < 3; ++q) {
        const int i0 = q * 256 + lane * 4;   // local window index
        if (i0 < K2_WLDSL) {
            const int gi = wbase + i0;       // global-in-tile index
            float4 p0v = make_float4(0.f, 0.f, 0.f, 0.f);
            float4 p1v = make_float4(0.f, 0.f, 0.f, 0.f);
            if (gi + 3 < cnt) {
                float4 a4 = *(const float4*)(ar0 + gi);
                float4 c4 = *(const float4*)(ai0 + gi);
                float4 d4 = *(const float4*)(ar1 + gi);
                float4 e4 = *(const float4*)(ai1 + gi);
                p0v.x = fmaf(a4.x, a4.x, c4.x * c4.x);
                p0v.y = fmaf(a4.y, a4.y, c4.y * c4.y);
                p0v.z = fmaf(a4.z, a4.z, c4.z * c4.z);
                p0v.w = fmaf(a4.w, a4.w, c4.w * c4.w);
                p1v.x = fmaf(d4.x, d4.x, e4.x * e4.x);
                p1v.y = fmaf(d4.y, d4.y, e4.y * e4.y);
                p1v.z = fmaf(d4.z, d4.z, e4.z * e4.z);
                p1v.w = fmaf(d4.w, d4.w, e4.w * e4.w);
            } else {
                float p0a[4] = {0.f, 0.f, 0.f, 0.f};
                float p1a[4] = {0.f, 0.f, 0.f, 0.f};
                #pragma unroll
                for (int u = 0; u < 4; ++u) {
                    const int i = gi + u;
                    if (i < cnt) {
                        float a = ar0[i], c = ai0[i];
                        float d = ar1[i], e = ai1[i];
                        p0a[u] = fmaf(a, a, c * c);
                        p1a[u] = fmaf(d, d, e * e);
                    }
                }
                p0v = make_float4(p0a[0], p0a[1], p0a[2], p0a[3]);
                p1v = make_float4(p1a[0], p1a[1], p1a[2], p1a[3]);
            }
            const int p = SWZ(i0);   // i0%32 <= 28 -> 4 contiguous, 16B-aligned
            *(float4*)&sp0[p] = p0v;
            *(float4*)&sp1[p] = p1v;
        }
    }

    // ---- hoisted rotation operand loads (issue-early; drain under conv) ----
    const int t0 = wbase + lane * 8;         // global-in-tile output base
    const int lt0 = lane * 8;                // local-in-window output base
    float ra0[8], rb0[8], ra1[8], rb1[8];
    {
        const float* art0 = ar0 + t0 + NTAPS_C / 2;   // = AR[...][tg+50]
        const float* ait0 = ai0 + t0 + NTAPS_C / 2;
        const float* art1 = ar1 + t0 + NTAPS_C / 2;
        const float* ait1 = ai1 + t0 + NTAPS_C / 2;
        #pragma unroll
        for (int j = 0; j < 8; ++j) {
            ra0[j] = art0[j]; rb0[j] = ait0[j];
            ra1[j] = art1[j]; rb1[j] = ait1[j];
        }
    }

    // fence LDS writes -> reads within the wave (no block barrier needed)
    asm volatile("s_waitcnt lgkmcnt(0)" ::: "memory");
    __builtin_amdgcn_sched_barrier(0);

    if (t0 >= nout) return;

    float th0[8], th1[8];
    #pragma unroll
    for (int j = 0; j < 8; ++j) { th0[j] = 0.f; th1[j] = 0.f; }
    const float* nkb = NKg + b * 4 * NKP;

    const int a0 = SWZ(lt0 + 16), a1 = SWZ(lt0 + 20), a2 = SWZ(lt0 + 24), a3 = SWZ(lt0 + 28);
    const int a4 = SWZ(lt0 + 32), a5 = SWZ(lt0 + 36), a6 = SWZ(lt0 + 40), a7 = SWZ(lt0 + 44);

    for (int im = 0; im < 2; ++im) {
        const float* sp  = im ? sp1 : sp0;
        const float* nkA = nkb + (0 * 2 + im) * NKP;   // output mode 0
        const float* nkB = nkb + (1 * 2 + im) * NKP;   // output mode 1
        float U[8], V[8], N[8];
        LD4V(U[0],U[1],U[2],U[3], sp[SWZ(lt0)]);
        LD4V(U[4],U[5],U[6],U[7], sp[SWZ(lt0 + 4)]);
        LD4V(V[0],V[1],V[2],V[3], sp[SWZ(lt0 + 8)]);
        LD4V(V[4],V[5],V[6],V[7], sp[SWZ(lt0 + 12)]);
        // 104 padded taps = 13 chunks (coeffs 101..103 are zero)
        N_CH8(U, V, N, a0,       a1,        0);
        N_CH8(V, N, U, a2,       a3,        8);
        N_CH8(N, U, V, a4,       a5,       16);
        N_CH8(U, V, N, a6,       a7,       24);
        N_CH8(V, N, U, a0 + 36,  a1 + 36,  32);
        N_CH8(N, U, V, a2 + 36,  a3 + 36,  40);
        N_CH8(U, V, N, a4 + 36,  a5 + 36,  48);
        N_CH8(V, N, U, a6 + 36,  a7 + 36,  56);
        N_CH8(N, U, V, a0 + 72,  a1 + 72,  64);
        N_CH8(U, V, N, a2 + 72,  a3 + 72,  72);
        N_CH8(V, N, U, a4 + 72,  a5 + 72,  80);
        N_CH8(N, U, V, a6 + 72,  a7 + 72,  88);
        N_CH8(U, V, N, a0 + 108, a1 + 108, 96);
    }

    const float coef = COEF[b];
    const int tg = tile0 + t0;

    float or0[8], oi0[8], or1[8], oi1[8];
    #pragma unroll
    for (int j = 0; j < 8; ++j) {
        const float x0 = th0[j] * coef;
        const float x1 = th1[j] * coef;
        const float s0 = __sinf(x0), c0 = __cosf(x0);
        const float s1 = __sinf(x1), c1 = __cosf(x1);
        float a0v = ra0[j], b0v = rb0[j];
        float a1v = ra1[j], b1v = rb1[j];
        or0[j] = fmaf(a0v, c0, -b0v * s0);
        oi0[j] = fmaf(a0v, s0,  b0v * c0);
        or1[j] = fmaf(a1v, c1, -b1v * s1);
        oi1[j] = fmaf(a1v, s1,  b1v * c1);
    }

    const int rem = nout - t0;
    if (finalstep) {
        // out[b][t][c][ri] contiguous float4 per t
        float4* op = (float4*)(OUT + (size_t)(b * Lb + tg) * 4);
        if (rem >= 8) {
            #pragma unroll
            for (int j = 0; j < 8; ++j) op[j] = make_float4(or0[j], oi0[j], or1[j], oi1[j]);
        } else {
            for (int j = 0; j < rem; ++j) op[j] = make_float4(or0[j], oi0[j], or1[j], oi1[j]);
        }
    } else {
        float* xr0 = XR + (size_t)(2 * b + 0) * SSTR + tg;
        float* xi0 = XI + (size_t)(2 * b + 0) * SSTR + tg;
        float* xr1 = XR + (size_t)(2 * b + 1) * SSTR + tg;
        float* xi1 = XI + (size_t)(2 * b + 1) * SSTR + tg;
        if (rem >= 8) {
            ((float4*)xr0)[0] = make_float4(or0[0], or0[1], or0[2], or0[3]);
            ((float4*)xr0)[1] = make_float4(or0[4], or0[5], or0[6], or0[7]);
            ((float4*)xi0)[0] = make_float4(oi0[0], oi0[1], oi0[2], oi0[3]);
            ((float4*)xi0)[1] = make_float4(oi0[4], oi0[5], oi0[6], oi0[7]);
            ((float4*)xr1)[0] = make_float4(or1[0], or1[1], or1[2], or1[3]);
            ((float4*)xr1)[1] = make_float4(or1[4], or1[5], or1[6], or1[7]);
            ((float4*)xi1)[0] = make_float4(oi1[0], oi1[1], oi1[2], oi1[3]);
            ((float4*)xi1)[1] = make_float4(oi1[4], oi1[5], oi1[6], oi1[7]);
        } else {
            for (int j = 0; j < rem; ++j) {
                xr0[j] = or0[j]; xi0[j] = oi0[j];
                xr1[j] = or1[j]; xi1[j] = oi1[j];
            }
        }
    }
}

// ---------------- launch ----------------
extern "C" void kernel_launch(void* const* d_in, const int* in_sizes, int n_in,
                              void* d_out, int out_size, void* d_ws, size_t ws_size,
                              hipStream_t stream)
{
    const float* x_real = (const float*)d_in[0];
    const float* x_imag = (const float*)d_in[1];
    const float* task   = (const float*)d_in[2];
    const float* W1     = (const float*)d_in[3];
    const float* b1     = (const float*)d_in[4];
    const float* W2     = (const float*)d_in[5];
    const float* b2     = (const float*)d_in[6];
    float* out = (float*)d_out;
    float* ws  = (float*)d_ws;

    float* HR   = ws;
    float* HI   = HR + B_C * DTAPS_C;
    float* NKg  = HI + B_C * DTAPS_C;
    float* COEF = NKg + B_C * 4 * NKP;
    float* Gb   = ws + 16384;                       // B*4096 complex = 32768 f
    float* XR = ws + 16384 + 32768;
    float* XI = XR + (size_t)B_C * 2 * SEQ_C;
    float* AR = XI + (size_t)B_C * 2 * SEQ_C;
    float* AI = AR + (size_t)B_C * 2 * SEQ_C;

    build_disp<<<dim3(32, B_C), 256, 0, stream>>>(task, HR, HI);
    build_nk<<<1, 512, 0, stream>>>(task, W1, b1, W2, b2, NKg, COEF);
    build_G<<<dim3(128, B_C), 256, 0, stream>>>(HR, HI, Gb);
    {
        int n = B_C * SEQ_C;
        transpose_in<<<(n + 255) / 256, 256, 0, stream>>>(x_real, x_imag, XR, XI);
    }

    int L = SEQ_C;
    for (int s = 0; s < STEPS_C; ++s) {
        const int La = L - (DTAPS_C - 1);     // after dispersion FIR
        const int Lb = La - (NTAPS_C - 1);    // after nonlinear conv + trim
        dim3 g1((La + FSTEP - 1) / FSTEP, B_C * NM);
        disp_fft<<<g1, 256, 0, stream>>>(XR, XI, Gb, AR, AI, La);
        dim3 g2((Lb + K2_TILE - 1) / K2_TILE, B_C);
        nl_rotate<<<g2, K2_BLOCK, 0, stream>>>(AR, AI, NKg, COEF, XR, XI, out,
                                               Lb, (s == STEPS_C - 1) ? 1 : 0);
        L = Lb;
    }
}